// Round 1
// baseline (3641.142 us; speedup 1.0000x reference)
//
#include <hip/hip_runtime.h>

// ---------------------------------------------------------------------------
// SpatialGCN: 3x (GCNConv -> LayerNorm -> ReLU[except last])
// N=50000 nodes, E=800000 edges, dims 128->128->128->64, all f32.
//
// Per layer:
//   gemm_init:  H = X @ W            (also AGG = H * dinv^2 + b  : self-loop+bias)
//   scatter:    AGG[dst] += H[src] * (dinv[src]*w*dinv[dst])     (atomics)
//   ln:         row-wise LayerNorm (+ReLU), in place
// deg/dinv computed once (edge_weight fixed across layers).
// ---------------------------------------------------------------------------

static constexpr int BM = 64;   // rows per GEMM block
static constexpr int KC = 32;   // k-chunk staged in LDS

// ---------------- degree / dinv ----------------
__global__ __launch_bounds__(256) void deg_kernel(
    const int* __restrict__ dst, const float* __restrict__ ew,
    float* __restrict__ deg, int nE)
{
    int e = blockIdx.x * 256 + threadIdx.x;
    if (e < nE) unsafeAtomicAdd(&deg[dst[e]], ew[e]);
}

__global__ __launch_bounds__(256) void dinv_kernel(float* __restrict__ deg, int n)
{
    int i = blockIdx.x * 256 + threadIdx.x;
    if (i < n) deg[i] = rsqrtf(deg[i] + 1.0f);   // +1 = self-loop weight; deg>0 always
}

// ---------------- GEMM (X[n,128] @ W[128,DOUT]) + self-loop/bias epilogue ----
template<int DOUT>
__global__ __launch_bounds__(256) void gemm_init_kernel(
    const float* __restrict__ X, const float* __restrict__ W,
    const float* __restrict__ bias, const float* __restrict__ dinv,
    float* __restrict__ H, float* __restrict__ AGG, int n)
{
    __shared__ float wl[KC * DOUT];
    __shared__ float xl[BM][132];          // +4 pad: conflict-free b128 reads
    const int tid  = threadIdx.x;
    const int row0 = blockIdx.x * BM;

    // stage X tile [BM][128]
    for (int i = tid; i < BM * 32; i += 256) {
        const int r = i >> 5, c4 = i & 31;
        const int gr = row0 + r;
        float4 v = make_float4(0.f, 0.f, 0.f, 0.f);
        if (gr < n) v = ((const float4*)(X + (size_t)gr * 128))[c4];
        *(float4*)&xl[r][c4 * 4] = v;
    }

    constexpr int CG  = DOUT / 4;     // col-groups (float4 wide)
    constexpr int RT  = 256 / CG;     // row-threads
    constexpr int RPT = BM / RT;      // rows per thread (interleaved by RT)
    const int cg = tid % CG;
    const int rt = tid / CG;

    float4 acc[RPT];
#pragma unroll
    for (int r = 0; r < RPT; ++r) acc[r] = make_float4(0.f, 0.f, 0.f, 0.f);

    for (int kc = 0; kc < 128 / KC; ++kc) {
        __syncthreads();                               // xl ready / prev wl consumed
        for (int i = tid; i < KC * CG; i += 256)       // stage W chunk [KC][DOUT]
            ((float4*)wl)[i] = ((const float4*)(W + (size_t)kc * KC * DOUT))[i];
        __syncthreads();
#pragma unroll
        for (int k4 = 0; k4 < KC / 4; ++k4) {
            float4 xv[RPT];
#pragma unroll
            for (int r = 0; r < RPT; ++r)
                xv[r] = *(const float4*)&xl[rt + RT * r][kc * KC + k4 * 4];
#pragma unroll
            for (int kk = 0; kk < 4; ++kk) {
                const float4 wv = ((const float4*)&wl[(k4 * 4 + kk) * DOUT])[cg];
#pragma unroll
                for (int r = 0; r < RPT; ++r) {
                    const float xs = kk == 0 ? xv[r].x : kk == 1 ? xv[r].y
                                   : kk == 2 ? xv[r].z : xv[r].w;
                    acc[r].x = fmaf(xs, wv.x, acc[r].x);
                    acc[r].y = fmaf(xs, wv.y, acc[r].y);
                    acc[r].z = fmaf(xs, wv.z, acc[r].z);
                    acc[r].w = fmaf(xs, wv.w, acc[r].w);
                }
            }
        }
    }

    const float4 bv = ((const float4*)bias)[cg];
#pragma unroll
    for (int r = 0; r < RPT; ++r) {
        const int gr = row0 + rt + RT * r;
        if (gr >= n) continue;
        ((float4*)(H + (size_t)gr * DOUT))[cg] = acc[r];
        const float di = dinv[gr];
        const float sn = di * di;                      // self-loop norm = 1/deg
        float4 av;
        av.x = fmaf(acc[r].x, sn, bv.x);
        av.y = fmaf(acc[r].y, sn, bv.y);
        av.z = fmaf(acc[r].z, sn, bv.z);
        av.w = fmaf(acc[r].w, sn, bv.w);
        ((float4*)(AGG + (size_t)gr * DOUT))[cg] = av;
    }
}

// ---------------- edge scatter: AGG[dst] += H[src] * norm ----------------
template<int D>
__global__ __launch_bounds__(256) void scatter_kernel(
    const int* __restrict__ src, const int* __restrict__ dst,
    const float* __restrict__ ew, const float* __restrict__ dinv,
    const float* __restrict__ H, float* __restrict__ AGG, int nE)
{
    constexpr int TPE = D / 4;               // threads per edge (float4 each)
    const int tid = blockIdx.x * 256 + threadIdx.x;
    const int e = tid / TPE;
    if (e >= nE) return;
    const int f4 = tid % TPE;
    const int s = src[e], d = dst[e];
    const float nrm = dinv[s] * ew[e] * dinv[d];
    const float4 hv = ((const float4*)(H + (size_t)s * D))[f4];
    float* out = AGG + (size_t)d * D + f4 * 4;
    unsafeAtomicAdd(out + 0, hv.x * nrm);
    unsafeAtomicAdd(out + 1, hv.y * nrm);
    unsafeAtomicAdd(out + 2, hv.z * nrm);
    unsafeAtomicAdd(out + 3, hv.w * nrm);
}

// ---------------- row LayerNorm (+optional ReLU), one wave per row ----------
template<int D, bool RELU>
__global__ __launch_bounds__(256) void ln_kernel(
    const float* __restrict__ A, const float* __restrict__ g,
    const float* __restrict__ t, float* __restrict__ OUT, int n)
{
    constexpr int PL = D / 64;               // elems per lane
    const int lane = threadIdx.x & 63;
    const int row = blockIdx.x * 4 + (threadIdx.x >> 6);
    if (row >= n) return;
    const float* a = A + (size_t)row * D;
    float v[PL];
    float s = 0.f;
#pragma unroll
    for (int i = 0; i < PL; ++i) { v[i] = a[lane * PL + i]; s += v[i]; }
#pragma unroll
    for (int off = 32; off; off >>= 1) s += __shfl_xor(s, off);
    const float m = s * (1.f / D);
    float s2 = 0.f;
#pragma unroll
    for (int i = 0; i < PL; ++i) { v[i] -= m; s2 += v[i] * v[i]; }
#pragma unroll
    for (int off = 32; off; off >>= 1) s2 += __shfl_xor(s2, off);
    const float rsq = rsqrtf(s2 * (1.f / D) + 1e-5f);
    float* o = OUT + (size_t)row * D;
#pragma unroll
    for (int i = 0; i < PL; ++i) {
        const int f = lane * PL + i;
        float r = v[i] * rsq * g[f] + t[f];
        if (RELU) r = fmaxf(r, 0.f);
        o[f] = r;
    }
}

// ---------------------------------------------------------------------------
extern "C" void kernel_launch(void* const* d_in, const int* in_sizes, int n_in,
                              void* d_out, int out_size, void* d_ws, size_t ws_size,
                              hipStream_t stream)
{
    const float* x  = (const float*)d_in[0];
    const int*   ei = (const int*)  d_in[1];
    const float* ew = (const float*)d_in[2];
    const float* W1 = (const float*)d_in[3];
    const float* b1 = (const float*)d_in[4];
    const float* g1 = (const float*)d_in[5];
    const float* t1 = (const float*)d_in[6];
    const float* W2 = (const float*)d_in[7];
    const float* b2 = (const float*)d_in[8];
    const float* g2 = (const float*)d_in[9];
    const float* t2 = (const float*)d_in[10];
    const float* W3 = (const float*)d_in[11];
    const float* b3 = (const float*)d_in[12];
    const float* g3 = (const float*)d_in[13];
    const float* t3 = (const float*)d_in[14];

    const int n  = in_sizes[0] / 128;
    const int nE = in_sizes[1] / 2;
    const int* srcv = ei;           // edge_index[0]
    const int* dstv = ei + nE;      // edge_index[1]

    // workspace: degv[n] | P[n*128] | Q[n*128]   (~51.5 MB)
    float* ws   = (float*)d_ws;
    float* degv = ws;
    float* P    = ws + (((size_t)n + 63) & ~(size_t)63);
    float* Q    = P + (size_t)n * 128;

    // dinv (once)
    hipMemsetAsync(degv, 0, (size_t)n * sizeof(float), stream);
    deg_kernel<<<(nE + 255) / 256, 256, 0, stream>>>(dstv, ew, degv, nE);
    dinv_kernel<<<(n + 255) / 256, 256, 0, stream>>>(degv, n);

    const int gb  = (n + BM - 1) / BM;
    const int lnb = (n + 3) / 4;
    const int sb128 = (int)(((size_t)nE * 32 + 255) / 256);
    const int sb64  = (int)(((size_t)nE * 16 + 255) / 256);

    // Layer 1: x -> Q
    gemm_init_kernel<128><<<gb, 256, 0, stream>>>(x, W1, b1, degv, P, Q, n);
    scatter_kernel<128><<<sb128, 256, 0, stream>>>(srcv, dstv, ew, degv, P, Q, nE);
    ln_kernel<128, true><<<lnb, 256, 0, stream>>>(Q, g1, t1, Q, n);

    // Layer 2: Q -> Q   (in-place AGG init is safe: each GEMM block stages its
    // own rows into LDS before the epilogue writes those same rows)
    gemm_init_kernel<128><<<gb, 256, 0, stream>>>(Q, W2, b2, degv, P, Q, n);
    scatter_kernel<128><<<sb128, 256, 0, stream>>>(srcv, dstv, ew, degv, P, Q, nE);
    ln_kernel<128, true><<<lnb, 256, 0, stream>>>(Q, g2, t2, Q, n);

    // Layer 3: Q -> d_out (H3 and AGG3 both live in the P region)
    float* H3 = P;
    float* A3 = P + (size_t)n * 64;
    gemm_init_kernel<64><<<gb, 256, 0, stream>>>(Q, W3, b3, degv, H3, A3, n);
    scatter_kernel<64><<<sb64, 256, 0, stream>>>(srcv, dstv, ew, degv, H3, A3, nE);
    ln_kernel<64, false><<<lnb, 256, 0, stream>>>(A3, g3, t3, (float*)d_out, n);
}

// Round 3
// 597.989 us; speedup vs baseline: 6.0890x; 6.0890x over previous
//
#include <hip/hip_runtime.h>

// ---------------------------------------------------------------------------
// SpatialGCN: 3x (GCNConv -> LayerNorm -> ReLU[except last])
// N=50000, E=800000, dims 128->128->128->64, f32.
//
// R1 change (resubmitted R2; never ran due to GPU timeout): scatter+atomics
// (92% of time, atomic-serialization-bound) replaced by CSR-by-dst build
// (once per call) + gather kernel, one wave per node, with self-loop+bias
// init and LayerNorm+ReLU fused in (row lives in wave regs).
// ---------------------------------------------------------------------------

static constexpr int BM = 64;   // rows per GEMM block
static constexpr int KC = 32;   // k-chunk staged in LDS

// ---------------- degree / dinv ----------------
__global__ __launch_bounds__(256) void deg_kernel(
    const int* __restrict__ dst, const float* __restrict__ ew,
    float* __restrict__ deg, int nE)
{
    int e = blockIdx.x * 256 + threadIdx.x;
    if (e < nE) unsafeAtomicAdd(&deg[dst[e]], ew[e]);
}

__global__ __launch_bounds__(256) void dinv_kernel(float* __restrict__ deg, int n)
{
    int i = blockIdx.x * 256 + threadIdx.x;
    if (i < n) deg[i] = rsqrtf(deg[i] + 1.0f);   // +1 = self-loop weight; deg>0 always
}

// ---------------- CSR build: hist -> scan -> fill ----------------
__global__ __launch_bounds__(256) void hist_kernel(
    const int* __restrict__ dst, int* __restrict__ cnt, int nE)
{
    int e = blockIdx.x * 256 + threadIdx.x;
    if (e < nE) atomicAdd(&cnt[dst[e]], 1);
}

// single-block chunked exclusive scan; also leaves a copy in cnt[] (fill cursor)
__global__ __launch_bounds__(1024) void scan_kernel(
    int* __restrict__ cnt, int* __restrict__ rowptr, int n)
{
    __shared__ int buf[1024];
    __shared__ int carry;
    if (threadIdx.x == 0) carry = 0;
    __syncthreads();
    for (int base = 0; base < n; base += 1024) {
        const int i = base + threadIdx.x;
        const int v = (i < n) ? cnt[i] : 0;
        buf[threadIdx.x] = v;
        __syncthreads();
        for (int off = 1; off < 1024; off <<= 1) {
            const int tt = (threadIdx.x >= off) ? buf[threadIdx.x - off] : 0;
            __syncthreads();
            buf[threadIdx.x] += tt;
            __syncthreads();
        }
        const int excl = buf[threadIdx.x] - v + carry;
        if (i < n) { rowptr[i] = excl; cnt[i] = excl; }   // cnt becomes fill cursor
        __syncthreads();
        if (threadIdx.x == 1023) carry += buf[1023];
        __syncthreads();
    }
    if (threadIdx.x == 0) rowptr[n] = carry;
}

__global__ __launch_bounds__(256) void fill_kernel(
    const int* __restrict__ src, const int* __restrict__ dst,
    const float* __restrict__ ew, const float* __restrict__ dinv,
    int* __restrict__ cursor, int2* __restrict__ edges, int nE)
{
    int e = blockIdx.x * 256 + threadIdx.x;
    if (e >= nE) return;
    const int s = src[e], d = dst[e];
    const float nrm = dinv[s] * ew[e] * dinv[d];
    const int pos = atomicAdd(&cursor[d], 1);
    edges[pos] = make_int2(s, __float_as_int(nrm));
}

// ---------------- GEMM: H = X[n,128] @ W[128,DOUT] ----------------
template<int DOUT>
__global__ __launch_bounds__(256) void gemm_kernel(
    const float* __restrict__ X, const float* __restrict__ W,
    float* __restrict__ H, int n)
{
    __shared__ float wl[KC * DOUT];
    __shared__ float xl[BM][132];          // +4 pad: conflict-free b128 reads
    const int tid  = threadIdx.x;
    const int row0 = blockIdx.x * BM;

    for (int i = tid; i < BM * 32; i += 256) {
        const int r = i >> 5, c4 = i & 31;
        const int gr = row0 + r;
        float4 v = make_float4(0.f, 0.f, 0.f, 0.f);
        if (gr < n) v = ((const float4*)(X + (size_t)gr * 128))[c4];
        *(float4*)&xl[r][c4 * 4] = v;
    }

    constexpr int CG  = DOUT / 4;
    constexpr int RT  = 256 / CG;
    constexpr int RPT = BM / RT;
    const int cg = tid % CG;
    const int rt = tid / CG;

    float4 acc[RPT];
#pragma unroll
    for (int r = 0; r < RPT; ++r) acc[r] = make_float4(0.f, 0.f, 0.f, 0.f);

    for (int kc = 0; kc < 128 / KC; ++kc) {
        __syncthreads();
        for (int i = tid; i < KC * CG; i += 256)
            ((float4*)wl)[i] = ((const float4*)(W + (size_t)kc * KC * DOUT))[i];
        __syncthreads();
#pragma unroll
        for (int k4 = 0; k4 < KC / 4; ++k4) {
            float4 xv[RPT];
#pragma unroll
            for (int r = 0; r < RPT; ++r)
                xv[r] = *(const float4*)&xl[rt + RT * r][kc * KC + k4 * 4];
#pragma unroll
            for (int kk = 0; kk < 4; ++kk) {
                const float4 wv = ((const float4*)&wl[(k4 * 4 + kk) * DOUT])[cg];
#pragma unroll
                for (int r = 0; r < RPT; ++r) {
                    const float xs = kk == 0 ? xv[r].x : kk == 1 ? xv[r].y
                                   : kk == 2 ? xv[r].z : xv[r].w;
                    acc[r].x = fmaf(xs, wv.x, acc[r].x);
                    acc[r].y = fmaf(xs, wv.y, acc[r].y);
                    acc[r].z = fmaf(xs, wv.z, acc[r].z);
                    acc[r].w = fmaf(xs, wv.w, acc[r].w);
                }
            }
        }
    }

#pragma unroll
    for (int r = 0; r < RPT; ++r) {
        const int gr = row0 + rt + RT * r;
        if (gr < n) ((float4*)(H + (size_t)gr * DOUT))[cg] = acc[r];
    }
}

// ------- gather + self-loop/bias + LayerNorm(+ReLU), one wave per node -------
template<int D, bool RELU>
__global__ __launch_bounds__(256) void gather_ln_kernel(
    const float* __restrict__ H, const int2* __restrict__ edges,
    const int* __restrict__ rowptr, const float* __restrict__ dinv,
    const float* __restrict__ bias, const float* __restrict__ g,
    const float* __restrict__ t, float* __restrict__ OUT, int n)
{
    constexpr int PL = D / 64;               // elems per lane
    const int lane = threadIdx.x & 63;
    const int node = blockIdx.x * 4 + (threadIdx.x >> 6);
    if (node >= n) return;

    const float di = dinv[node];
    const float sn = di * di;                // self-loop norm = 1/deg
    float acc[PL];
    const float* hd = H + (size_t)node * D + lane * PL;
#pragma unroll
    for (int i = 0; i < PL; ++i) acc[i] = fmaf(hd[i], sn, bias[lane * PL + i]);

    const int k0 = rowptr[node], k1 = rowptr[node + 1];
    for (int base = k0; base < k1; base += 64) {
        int2 ed = make_int2(0, 0);
        if (base + lane < k1) ed = edges[base + lane];
        const int cnt = min(64, k1 - base);
        for (int j = 0; j < cnt; ++j) {
            const int   s   = __shfl(ed.x, j);
            const float nrm = __int_as_float(__shfl(ed.y, j));
            const float* hs = H + (size_t)s * D + lane * PL;
#pragma unroll
            for (int i = 0; i < PL; ++i) acc[i] = fmaf(hs[i], nrm, acc[i]);
        }
    }

    // LayerNorm across the wave (full row is in wave registers)
    float s1 = 0.f;
#pragma unroll
    for (int i = 0; i < PL; ++i) s1 += acc[i];
#pragma unroll
    for (int off = 32; off; off >>= 1) s1 += __shfl_xor(s1, off);
    const float m = s1 * (1.f / D);
    float s2 = 0.f;
#pragma unroll
    for (int i = 0; i < PL; ++i) { acc[i] -= m; s2 += acc[i] * acc[i]; }
#pragma unroll
    for (int off = 32; off; off >>= 1) s2 += __shfl_xor(s2, off);
    const float rs = rsqrtf(s2 * (1.f / D) + 1e-5f);

    float* o = OUT + (size_t)node * D + lane * PL;
#pragma unroll
    for (int i = 0; i < PL; ++i) {
        float r = fmaf(acc[i] * rs, g[lane * PL + i], t[lane * PL + i]);
        if (RELU) r = fmaxf(r, 0.f);
        o[i] = r;
    }
}

// ---------------------------------------------------------------------------
extern "C" void kernel_launch(void* const* d_in, const int* in_sizes, int n_in,
                              void* d_out, int out_size, void* d_ws, size_t ws_size,
                              hipStream_t stream)
{
    const float* x  = (const float*)d_in[0];
    const int*   ei = (const int*)  d_in[1];
    const float* ew = (const float*)d_in[2];
    const float* W1 = (const float*)d_in[3];
    const float* b1 = (const float*)d_in[4];
    const float* g1 = (const float*)d_in[5];
    const float* t1 = (const float*)d_in[6];
    const float* W2 = (const float*)d_in[7];
    const float* b2 = (const float*)d_in[8];
    const float* g2 = (const float*)d_in[9];
    const float* t2 = (const float*)d_in[10];
    const float* W3 = (const float*)d_in[11];
    const float* b3 = (const float*)d_in[12];
    const float* g3 = (const float*)d_in[13];
    const float* t3 = (const float*)d_in[14];

    const int n  = in_sizes[0] / 128;
    const int nE = in_sizes[1] / 2;
    const int* srcv = ei;           // edge_index[0]
    const int* dstv = ei + nE;      // edge_index[1]

    const size_t na = ((size_t)n + 63) & ~(size_t)63;

    // ws layout: degv[na] f32 | cnt/cursor[na] i32 | rowptr[na+64] i32 |
    //            edges[E] int2 | P[n*128] f32 | Q[n*128] f32   (~58.5 MB)
    float* degv   = (float*)d_ws;
    int*   cnt    = (int*)(degv + na);
    int*   rowptr = cnt + na;
    int2*  edges  = (int2*)(rowptr + na + 64);
    float* P      = (float*)(edges + nE);
    float* Q      = P + (size_t)n * 128;

    // zero degv + cnt in one shot (contiguous)
    hipMemsetAsync(degv, 0, na * 2 * sizeof(float), stream);

    // graph prep (once per call; reused by all 3 layers)
    deg_kernel <<<(nE + 255) / 256, 256, 0, stream>>>(dstv, ew, degv, nE);
    dinv_kernel<<<(n  + 255) / 256, 256, 0, stream>>>(degv, n);
    hist_kernel<<<(nE + 255) / 256, 256, 0, stream>>>(dstv, cnt, nE);
    scan_kernel<<<1, 1024, 0, stream>>>(cnt, rowptr, n);
    fill_kernel<<<(nE + 255) / 256, 256, 0, stream>>>(srcv, dstv, ew, degv, cnt, edges, nE);

    const int gb  = (n + BM - 1) / BM;
    const int nb  = (n + 3) / 4;

    // Layer 1: x -> P(H) -> Q
    gemm_kernel<128><<<gb, 256, 0, stream>>>(x, W1, P, n);
    gather_ln_kernel<128, true><<<nb, 256, 0, stream>>>(P, edges, rowptr, degv, b1, g1, t1, Q, n);

    // Layer 2: Q -> P(H) -> Q
    gemm_kernel<128><<<gb, 256, 0, stream>>>(Q, W2, P, n);
    gather_ln_kernel<128, true><<<nb, 256, 0, stream>>>(P, edges, rowptr, degv, b2, g2, t2, Q, n);

    // Layer 3: Q -> P(H3, n*64) -> d_out
    gemm_kernel<64><<<gb, 256, 0, stream>>>(Q, W3, P, n);
    gather_ln_kernel<64, false><<<nb, 256, 0, stream>>>(P, edges, rowptr, degv, b3, g3, t3, (float*)d_out, n);
}

// Round 4
// 468.476 us; speedup vs baseline: 7.7723x; 1.2765x over previous
//
#include <hip/hip_runtime.h>

// ---------------------------------------------------------------------------
// SpatialGCN: 3x (GCNConv -> LayerNorm -> ReLU[except last])
// N=50000, E=800000, dims 128->128->128->64, f32.
//
// R3 changes (from profile: scan_kernel 94us single-block = 16% of total):
//  - hierarchical 3-kernel scan (full occupancy) replaces single-block scan
//  - deg+hist fused into one edge pass; dinv fused into scan partials pass
//  - gather inner loop unrolled x4 (4 outstanding gather loads per wave)
// ---------------------------------------------------------------------------

static constexpr int BM = 64;   // rows per GEMM block
static constexpr int KC = 32;   // k-chunk staged in LDS

// ---------------- fused degree-sum + edge histogram ----------------
__global__ __launch_bounds__(256) void deghist_kernel(
    const int* __restrict__ dst, const float* __restrict__ ew,
    float* __restrict__ deg, int* __restrict__ cnt, int nE)
{
    int e = blockIdx.x * 256 + threadIdx.x;
    if (e < nE) {
        const int d = dst[e];
        unsafeAtomicAdd(&deg[d], ew[e]);
        atomicAdd(&cnt[d], 1);
    }
}

// ---------------- hierarchical scan (A: partials + dinv) ----------------
__global__ __launch_bounds__(256) void partial_dinv_kernel(
    const int* __restrict__ cnt, int* __restrict__ partials,
    float* __restrict__ deg, int n)
{
    const int b = blockIdx.x;
    const int i = b * 256 + threadIdx.x;
    if (i < n) deg[i] = rsqrtf(deg[i] + 1.0f);   // dinv; +1 = self-loop weight
    int v = (i < n) ? cnt[i] : 0;
#pragma unroll
    for (int off = 32; off; off >>= 1) v += __shfl_xor(v, off);
    __shared__ int red[4];
    if ((threadIdx.x & 63) == 0) red[threadIdx.x >> 6] = v;
    __syncthreads();
    if (threadIdx.x == 0) partials[b] = red[0] + red[1] + red[2] + red[3];
}

// ---------------- B: exclusive scan of <=256 block partials ----------------
__global__ __launch_bounds__(256) void scanp_kernel(
    int* __restrict__ partials, int* __restrict__ rowptr, int n, int nblk)
{
    __shared__ int buf[256];
    const int v = (threadIdx.x < nblk) ? partials[threadIdx.x] : 0;
    buf[threadIdx.x] = v;
    __syncthreads();
    for (int off = 1; off < 256; off <<= 1) {
        const int t = (threadIdx.x >= off) ? buf[threadIdx.x - off] : 0;
        __syncthreads();
        buf[threadIdx.x] += t;
        __syncthreads();
    }
    if (threadIdx.x < nblk) partials[threadIdx.x] = buf[threadIdx.x] - v;  // exclusive
    if (threadIdx.x == 255) rowptr[n] = buf[255];                          // total = E
}

// ---------------- C: intra-block scan + offset -> rowptr & cursor ----------
__global__ __launch_bounds__(256) void scanf_kernel(
    int* __restrict__ cnt, const int* __restrict__ partials,
    int* __restrict__ rowptr, int n)
{
    __shared__ int buf[256];
    const int b = blockIdx.x;
    const int i = b * 256 + threadIdx.x;
    const int v = (i < n) ? cnt[i] : 0;
    buf[threadIdx.x] = v;
    __syncthreads();
    for (int off = 1; off < 256; off <<= 1) {
        const int t = (threadIdx.x >= off) ? buf[threadIdx.x - off] : 0;
        __syncthreads();
        buf[threadIdx.x] += t;
        __syncthreads();
    }
    if (i < n) {
        const int ex = buf[threadIdx.x] - v + partials[b];
        rowptr[i] = ex;
        cnt[i]    = ex;                     // cnt becomes the fill cursor
    }
}

// ---------------- fill CSR with precomputed per-edge norm ----------------
__global__ __launch_bounds__(256) void fill_kernel(
    const int* __restrict__ src, const int* __restrict__ dst,
    const float* __restrict__ ew, const float* __restrict__ dinv,
    int* __restrict__ cursor, int2* __restrict__ edges, int nE)
{
    int e = blockIdx.x * 256 + threadIdx.x;
    if (e >= nE) return;
    const int s = src[e], d = dst[e];
    const float nrm = dinv[s] * ew[e] * dinv[d];
    const int pos = atomicAdd(&cursor[d], 1);
    edges[pos] = make_int2(s, __float_as_int(nrm));
}

// ---------------- GEMM: H = X[n,128] @ W[128,DOUT] ----------------
template<int DOUT>
__global__ __launch_bounds__(256) void gemm_kernel(
    const float* __restrict__ X, const float* __restrict__ W,
    float* __restrict__ H, int n)
{
    __shared__ float wl[KC * DOUT];
    __shared__ float xl[BM][132];          // +4 pad: conflict-free b128 reads
    const int tid  = threadIdx.x;
    const int row0 = blockIdx.x * BM;

    for (int i = tid; i < BM * 32; i += 256) {
        const int r = i >> 5, c4 = i & 31;
        const int gr = row0 + r;
        float4 v = make_float4(0.f, 0.f, 0.f, 0.f);
        if (gr < n) v = ((const float4*)(X + (size_t)gr * 128))[c4];
        *(float4*)&xl[r][c4 * 4] = v;
    }

    constexpr int CG  = DOUT / 4;
    constexpr int RT  = 256 / CG;
    constexpr int RPT = BM / RT;
    const int cg = tid % CG;
    const int rt = tid / CG;

    float4 acc[RPT];
#pragma unroll
    for (int r = 0; r < RPT; ++r) acc[r] = make_float4(0.f, 0.f, 0.f, 0.f);

    for (int kc = 0; kc < 128 / KC; ++kc) {
        __syncthreads();
        for (int i = tid; i < KC * CG; i += 256)
            ((float4*)wl)[i] = ((const float4*)(W + (size_t)kc * KC * DOUT))[i];
        __syncthreads();
#pragma unroll
        for (int k4 = 0; k4 < KC / 4; ++k4) {
            float4 xv[RPT];
#pragma unroll
            for (int r = 0; r < RPT; ++r)
                xv[r] = *(const float4*)&xl[rt + RT * r][kc * KC + k4 * 4];
#pragma unroll
            for (int kk = 0; kk < 4; ++kk) {
                const float4 wv = ((const float4*)&wl[(k4 * 4 + kk) * DOUT])[cg];
#pragma unroll
                for (int r = 0; r < RPT; ++r) {
                    const float xs = kk == 0 ? xv[r].x : kk == 1 ? xv[r].y
                                   : kk == 2 ? xv[r].z : xv[r].w;
                    acc[r].x = fmaf(xs, wv.x, acc[r].x);
                    acc[r].y = fmaf(xs, wv.y, acc[r].y);
                    acc[r].z = fmaf(xs, wv.z, acc[r].z);
                    acc[r].w = fmaf(xs, wv.w, acc[r].w);
                }
            }
        }
    }

#pragma unroll
    for (int r = 0; r < RPT; ++r) {
        const int gr = row0 + rt + RT * r;
        if (gr < n) ((float4*)(H + (size_t)gr * DOUT))[cg] = acc[r];
    }
}

// ------- gather + self-loop/bias + LayerNorm(+ReLU), one wave per node -------
template<int D, bool RELU>
__global__ __launch_bounds__(256) void gather_ln_kernel(
    const float* __restrict__ H, const int2* __restrict__ edges,
    const int* __restrict__ rowptr, const float* __restrict__ dinv,
    const float* __restrict__ bias, const float* __restrict__ g,
    const float* __restrict__ t, float* __restrict__ OUT, int n)
{
    constexpr int PL = D / 64;               // elems per lane
    const int lane = threadIdx.x & 63;
    const int node = blockIdx.x * 4 + (threadIdx.x >> 6);
    if (node >= n) return;

    const float di = dinv[node];
    const float sn = di * di;                // self-loop norm = 1/deg
    float acc[PL];
    const float* hd = H + (size_t)node * D + lane * PL;
#pragma unroll
    for (int i = 0; i < PL; ++i) acc[i] = fmaf(hd[i], sn, bias[lane * PL + i]);

    const int k0 = rowptr[node], k1 = rowptr[node + 1];
    for (int base = k0; base < k1; base += 64) {
        int2 ed = make_int2(0, 0);
        if (base + lane < k1) ed = edges[base + lane];
        const int cnt = min(64, k1 - base);
        int j = 0;
        for (; j + 4 <= cnt; j += 4) {       // 4 independent gather chains in flight
#pragma unroll
            for (int u = 0; u < 4; ++u) {
                const int   s   = __shfl(ed.x, j + u);
                const float nrm = __int_as_float(__shfl(ed.y, j + u));
                const float* hs = H + (size_t)s * D + lane * PL;
#pragma unroll
                for (int i = 0; i < PL; ++i) acc[i] = fmaf(hs[i], nrm, acc[i]);
            }
        }
        for (; j < cnt; ++j) {
            const int   s   = __shfl(ed.x, j);
            const float nrm = __int_as_float(__shfl(ed.y, j));
            const float* hs = H + (size_t)s * D + lane * PL;
#pragma unroll
            for (int i = 0; i < PL; ++i) acc[i] = fmaf(hs[i], nrm, acc[i]);
        }
    }

    // LayerNorm across the wave (full row is in wave registers)
    float s1 = 0.f;
#pragma unroll
    for (int i = 0; i < PL; ++i) s1 += acc[i];
#pragma unroll
    for (int off = 32; off; off >>= 1) s1 += __shfl_xor(s1, off);
    const float m = s1 * (1.f / D);
    float s2 = 0.f;
#pragma unroll
    for (int i = 0; i < PL; ++i) { acc[i] -= m; s2 += acc[i] * acc[i]; }
#pragma unroll
    for (int off = 32; off; off >>= 1) s2 += __shfl_xor(s2, off);
    const float rs = rsqrtf(s2 * (1.f / D) + 1e-5f);

    float* o = OUT + (size_t)node * D + lane * PL;
#pragma unroll
    for (int i = 0; i < PL; ++i) {
        float r = fmaf(acc[i] * rs, g[lane * PL + i], t[lane * PL + i]);
        if (RELU) r = fmaxf(r, 0.f);
        o[i] = r;
    }
}

// ---------------------------------------------------------------------------
extern "C" void kernel_launch(void* const* d_in, const int* in_sizes, int n_in,
                              void* d_out, int out_size, void* d_ws, size_t ws_size,
                              hipStream_t stream)
{
    const float* x  = (const float*)d_in[0];
    const int*   ei = (const int*)  d_in[1];
    const float* ew = (const float*)d_in[2];
    const float* W1 = (const float*)d_in[3];
    const float* b1 = (const float*)d_in[4];
    const float* g1 = (const float*)d_in[5];
    const float* t1 = (const float*)d_in[6];
    const float* W2 = (const float*)d_in[7];
    const float* b2 = (const float*)d_in[8];
    const float* g2 = (const float*)d_in[9];
    const float* t2 = (const float*)d_in[10];
    const float* W3 = (const float*)d_in[11];
    const float* b3 = (const float*)d_in[12];
    const float* g3 = (const float*)d_in[13];
    const float* t3 = (const float*)d_in[14];

    const int n  = in_sizes[0] / 128;
    const int nE = in_sizes[1] / 2;
    const int* srcv = ei;           // edge_index[0]
    const int* dstv = ei + nE;      // edge_index[1]

    const size_t na   = ((size_t)n + 63) & ~(size_t)63;
    const int    nblk = (n + 255) / 256;    // scan blocks (<=256 required; 196 here)

    // ws: degv[na] f32 | cnt[na] i32 | rowptr[na+64] i32 | partials[256] i32 |
    //     edges[E] int2 | P[n*128] f32 | Q[n*128] f32
    float* degv     = (float*)d_ws;
    int*   cnt      = (int*)(degv + na);
    int*   rowptr   = cnt + na;
    int*   partials = rowptr + na + 64;
    int2*  edges    = (int2*)(partials + 256);
    float* P        = (float*)(edges + nE);
    float* Q        = P + (size_t)n * 128;

    // zero degv + cnt in one shot (contiguous)
    hipMemsetAsync(degv, 0, na * 2 * sizeof(float), stream);

    // graph prep (once per call; reused by all 3 layers)
    deghist_kernel     <<<(nE + 255) / 256, 256, 0, stream>>>(dstv, ew, degv, cnt, nE);
    partial_dinv_kernel<<<nblk, 256, 0, stream>>>(cnt, partials, degv, n);
    scanp_kernel       <<<1,    256, 0, stream>>>(partials, rowptr, n, nblk);
    scanf_kernel       <<<nblk, 256, 0, stream>>>(cnt, partials, rowptr, n);
    fill_kernel        <<<(nE + 255) / 256, 256, 0, stream>>>(srcv, dstv, ew, degv, cnt, edges, nE);

    const int gb = (n + BM - 1) / BM;
    const int nb = (n + 3) / 4;

    // Layer 1: x -> P(H) -> Q
    gemm_kernel<128><<<gb, 256, 0, stream>>>(x, W1, P, n);
    gather_ln_kernel<128, true><<<nb, 256, 0, stream>>>(P, edges, rowptr, degv, b1, g1, t1, Q, n);

    // Layer 2: Q -> P(H) -> Q
    gemm_kernel<128><<<gb, 256, 0, stream>>>(Q, W2, P, n);
    gather_ln_kernel<128, true><<<nb, 256, 0, stream>>>(P, edges, rowptr, degv, b2, g2, t2, Q, n);

    // Layer 3: Q -> P(H3, n*64) -> d_out
    gemm_kernel<64><<<gb, 256, 0, stream>>>(Q, W3, P, n);
    gather_ln_kernel<64, false><<<nb, 256, 0, stream>>>(P, edges, rowptr, degv, b3, g3, t3, (float*)d_out, n);
}

// Round 5
// 401.524 us; speedup vs baseline: 9.0683x; 1.1667x over previous
//
#include <hip/hip_runtime.h>

// ---------------------------------------------------------------------------
// SpatialGCN: 3x (GCNConv -> LayerNorm -> ReLU[except last])
// N=50000, E=800000, dims 128->128->128->64, f32.
//
// R4 changes (from profile: deghist 75us = atomic line-thrash; fill has the
// same atomic cursor pattern):
//  - ONE u64 atomic per edge packs {count:24b hi | sum(ew):40b fixed-point lo};
//    returned old value's high bits = edge's rank in its dst bucket
//  - fill pass becomes atomic-free: pos = rowptr[dst] + rank[e]
//  - rank buffer overlays P region (free until first GEMM)
// ---------------------------------------------------------------------------

static constexpr int BM = 64;   // rows per GEMM block
static constexpr int KC = 32;   // k-chunk staged in LDS
static constexpr float FXS  = 16777216.0f;        // 2^24
static constexpr float FXSI = 1.0f / 16777216.0f;

// ---- Pass A: one u64 atomic per edge -> deg-sum + histogram + rank --------
__global__ __launch_bounds__(256) void edge_pass_kernel(
    const int* __restrict__ dst, const float* __restrict__ ew,
    unsigned long long* __restrict__ packed, int* __restrict__ rank, int nE)
{
    int e = blockIdx.x * 256 + threadIdx.x;
    if (e >= nE) return;
    const int d = dst[e];
    const unsigned long long fx = (unsigned long long)__float2uint_rn(ew[e] * FXS);
    const unsigned long long old = atomicAdd(&packed[d], (1ULL << 40) | fx);
    rank[e] = (int)(old >> 40);
}

// ---- Pass B: dinv from packed + per-block count partials ------------------
__global__ __launch_bounds__(256) void dinv_partial_kernel(
    const unsigned long long* __restrict__ packed, int* __restrict__ partials,
    float* __restrict__ dinv, int n)
{
    const int b = blockIdx.x;
    const int i = b * 256 + threadIdx.x;
    int c = 0;
    if (i < n) {
        const unsigned long long p = packed[i];
        c = (int)(p >> 40);
        const float deg = (float)(p & ((1ULL << 40) - 1)) * FXSI;
        dinv[i] = rsqrtf(deg + 1.0f);       // +1 = self-loop weight
    }
#pragma unroll
    for (int off = 32; off; off >>= 1) c += __shfl_xor(c, off);
    __shared__ int red[4];
    if ((threadIdx.x & 63) == 0) red[threadIdx.x >> 6] = c;
    __syncthreads();
    if (threadIdx.x == 0) partials[b] = red[0] + red[1] + red[2] + red[3];
}

// ---- Pass C: exclusive scan of <=256 block partials -----------------------
__global__ __launch_bounds__(256) void scanp_kernel(
    int* __restrict__ partials, int* __restrict__ rowptr, int n, int nblk)
{
    __shared__ int buf[256];
    const int v = (threadIdx.x < nblk) ? partials[threadIdx.x] : 0;
    buf[threadIdx.x] = v;
    __syncthreads();
    for (int off = 1; off < 256; off <<= 1) {
        const int t = (threadIdx.x >= off) ? buf[threadIdx.x - off] : 0;
        __syncthreads();
        buf[threadIdx.x] += t;
        __syncthreads();
    }
    if (threadIdx.x < nblk) partials[threadIdx.x] = buf[threadIdx.x] - v;  // exclusive
    if (threadIdx.x == 255) rowptr[n] = buf[255];                          // total = E
}

// ---- Pass D: intra-block scan + offset -> rowptr --------------------------
__global__ __launch_bounds__(256) void scanf_kernel(
    const unsigned long long* __restrict__ packed, const int* __restrict__ partials,
    int* __restrict__ rowptr, int n)
{
    __shared__ int buf[256];
    const int b = blockIdx.x;
    const int i = b * 256 + threadIdx.x;
    const int v = (i < n) ? (int)(packed[i] >> 40) : 0;
    buf[threadIdx.x] = v;
    __syncthreads();
    for (int off = 1; off < 256; off <<= 1) {
        const int t = (threadIdx.x >= off) ? buf[threadIdx.x - off] : 0;
        __syncthreads();
        buf[threadIdx.x] += t;
        __syncthreads();
    }
    if (i < n) rowptr[i] = buf[threadIdx.x] - v + partials[b];
}

// ---- Pass E: atomic-free CSR fill -----------------------------------------
__global__ __launch_bounds__(256) void fill2_kernel(
    const int* __restrict__ src, const int* __restrict__ dst,
    const float* __restrict__ ew, const int* __restrict__ rank,
    const float* __restrict__ dinv, const int* __restrict__ rowptr,
    int2* __restrict__ edges, int nE)
{
    int e = blockIdx.x * 256 + threadIdx.x;
    if (e >= nE) return;
    const int s = src[e], d = dst[e];
    const float nrm = dinv[s] * ew[e] * dinv[d];
    edges[rowptr[d] + rank[e]] = make_int2(s, __float_as_int(nrm));
}

// ---------------- GEMM: H = X[n,128] @ W[128,DOUT] ----------------
template<int DOUT>
__global__ __launch_bounds__(256) void gemm_kernel(
    const float* __restrict__ X, const float* __restrict__ W,
    float* __restrict__ H, int n)
{
    __shared__ float wl[KC * DOUT];
    __shared__ float xl[BM][132];          // +4 pad: conflict-free b128 reads
    const int tid  = threadIdx.x;
    const int row0 = blockIdx.x * BM;

    for (int i = tid; i < BM * 32; i += 256) {
        const int r = i >> 5, c4 = i & 31;
        const int gr = row0 + r;
        float4 v = make_float4(0.f, 0.f, 0.f, 0.f);
        if (gr < n) v = ((const float4*)(X + (size_t)gr * 128))[c4];
        *(float4*)&xl[r][c4 * 4] = v;
    }

    constexpr int CG  = DOUT / 4;
    constexpr int RT  = 256 / CG;
    constexpr int RPT = BM / RT;
    const int cg = tid % CG;
    const int rt = tid / CG;

    float4 acc[RPT];
#pragma unroll
    for (int r = 0; r < RPT; ++r) acc[r] = make_float4(0.f, 0.f, 0.f, 0.f);

    for (int kc = 0; kc < 128 / KC; ++kc) {
        __syncthreads();
        for (int i = tid; i < KC * CG; i += 256)
            ((float4*)wl)[i] = ((const float4*)(W + (size_t)kc * KC * DOUT))[i];
        __syncthreads();
#pragma unroll
        for (int k4 = 0; k4 < KC / 4; ++k4) {
            float4 xv[RPT];
#pragma unroll
            for (int r = 0; r < RPT; ++r)
                xv[r] = *(const float4*)&xl[rt + RT * r][kc * KC + k4 * 4];
#pragma unroll
            for (int kk = 0; kk < 4; ++kk) {
                const float4 wv = ((const float4*)&wl[(k4 * 4 + kk) * DOUT])[cg];
#pragma unroll
                for (int r = 0; r < RPT; ++r) {
                    const float xs = kk == 0 ? xv[r].x : kk == 1 ? xv[r].y
                                   : kk == 2 ? xv[r].z : xv[r].w;
                    acc[r].x = fmaf(xs, wv.x, acc[r].x);
                    acc[r].y = fmaf(xs, wv.y, acc[r].y);
                    acc[r].z = fmaf(xs, wv.z, acc[r].z);
                    acc[r].w = fmaf(xs, wv.w, acc[r].w);
                }
            }
        }
    }

#pragma unroll
    for (int r = 0; r < RPT; ++r) {
        const int gr = row0 + rt + RT * r;
        if (gr < n) ((float4*)(H + (size_t)gr * DOUT))[cg] = acc[r];
    }
}

// ------- gather + self-loop/bias + LayerNorm(+ReLU), one wave per node -------
template<int D, bool RELU>
__global__ __launch_bounds__(256) void gather_ln_kernel(
    const float* __restrict__ H, const int2* __restrict__ edges,
    const int* __restrict__ rowptr, const float* __restrict__ dinv,
    const float* __restrict__ bias, const float* __restrict__ g,
    const float* __restrict__ t, float* __restrict__ OUT, int n)
{
    constexpr int PL = D / 64;               // elems per lane
    const int lane = threadIdx.x & 63;
    const int node = blockIdx.x * 4 + (threadIdx.x >> 6);
    if (node >= n) return;

    const float di = dinv[node];
    const float sn = di * di;                // self-loop norm = 1/deg
    float acc[PL];
    const float* hd = H + (size_t)node * D + lane * PL;
#pragma unroll
    for (int i = 0; i < PL; ++i) acc[i] = fmaf(hd[i], sn, bias[lane * PL + i]);

    const int k0 = rowptr[node], k1 = rowptr[node + 1];
    for (int base = k0; base < k1; base += 64) {
        int2 ed = make_int2(0, 0);
        if (base + lane < k1) ed = edges[base + lane];
        const int cnt = min(64, k1 - base);
        int j = 0;
        for (; j + 4 <= cnt; j += 4) {       // 4 independent gather chains in flight
#pragma unroll
            for (int u = 0; u < 4; ++u) {
                const int   s   = __shfl(ed.x, j + u);
                const float nrm = __int_as_float(__shfl(ed.y, j + u));
                const float* hs = H + (size_t)s * D + lane * PL;
#pragma unroll
                for (int i = 0; i < PL; ++i) acc[i] = fmaf(hs[i], nrm, acc[i]);
            }
        }
        for (; j < cnt; ++j) {
            const int   s   = __shfl(ed.x, j);
            const float nrm = __int_as_float(__shfl(ed.y, j));
            const float* hs = H + (size_t)s * D + lane * PL;
#pragma unroll
            for (int i = 0; i < PL; ++i) acc[i] = fmaf(hs[i], nrm, acc[i]);
        }
    }

    // LayerNorm across the wave (full row is in wave registers)
    float s1 = 0.f;
#pragma unroll
    for (int i = 0; i < PL; ++i) s1 += acc[i];
#pragma unroll
    for (int off = 32; off; off >>= 1) s1 += __shfl_xor(s1, off);
    const float m = s1 * (1.f / D);
    float s2 = 0.f;
#pragma unroll
    for (int i = 0; i < PL; ++i) { acc[i] -= m; s2 += acc[i] * acc[i]; }
#pragma unroll
    for (int off = 32; off; off >>= 1) s2 += __shfl_xor(s2, off);
    const float rs = rsqrtf(s2 * (1.f / D) + 1e-5f);

    float* o = OUT + (size_t)node * D + lane * PL;
#pragma unroll
    for (int i = 0; i < PL; ++i) {
        float r = fmaf(acc[i] * rs, g[lane * PL + i], t[lane * PL + i]);
        if (RELU) r = fmaxf(r, 0.f);
        o[i] = r;
    }
}

// ---------------------------------------------------------------------------
extern "C" void kernel_launch(void* const* d_in, const int* in_sizes, int n_in,
                              void* d_out, int out_size, void* d_ws, size_t ws_size,
                              hipStream_t stream)
{
    const float* x  = (const float*)d_in[0];
    const int*   ei = (const int*)  d_in[1];
    const float* ew = (const float*)d_in[2];
    const float* W1 = (const float*)d_in[3];
    const float* b1 = (const float*)d_in[4];
    const float* g1 = (const float*)d_in[5];
    const float* t1 = (const float*)d_in[6];
    const float* W2 = (const float*)d_in[7];
    const float* b2 = (const float*)d_in[8];
    const float* g2 = (const float*)d_in[9];
    const float* t2 = (const float*)d_in[10];
    const float* W3 = (const float*)d_in[11];
    const float* b3 = (const float*)d_in[12];
    const float* g3 = (const float*)d_in[13];
    const float* t3 = (const float*)d_in[14];

    const int n  = in_sizes[0] / 128;
    const int nE = in_sizes[1] / 2;
    const int* srcv = ei;           // edge_index[0]
    const int* dstv = ei + nE;      // edge_index[1]

    const size_t na   = ((size_t)n + 63) & ~(size_t)63;
    const int    nblk = (n + 255) / 256;    // scan blocks (<=256 required; 196 here)
    const int    eb   = (nE + 255) / 256;

    // ws: packed[na] u64 | dinv[na] f32 | rowptr[na+64] i32 | partials[256] i32 |
    //     edges[E] int2 | P[n*128] f32 | Q[n*128] f32
    // rank[nE] overlays P (free until first GEMM).
    unsigned long long* packed = (unsigned long long*)d_ws;
    float* dinv     = (float*)(packed + na);
    int*   rowptr   = (int*)(dinv + na);
    int*   partials = rowptr + na + 64;
    int2*  edges    = (int2*)(partials + 256);
    float* P        = (float*)(edges + nE);
    float* Q        = P + (size_t)n * 128;
    int*   rank     = (int*)P;

    hipMemsetAsync(packed, 0, na * sizeof(unsigned long long), stream);

    // graph prep (once per call; reused by all 3 layers)
    edge_pass_kernel  <<<eb,   256, 0, stream>>>(dstv, ew, packed, rank, nE);
    dinv_partial_kernel<<<nblk, 256, 0, stream>>>(packed, partials, dinv, n);
    scanp_kernel      <<<1,    256, 0, stream>>>(partials, rowptr, n, nblk);
    scanf_kernel      <<<nblk, 256, 0, stream>>>(packed, partials, rowptr, n);
    fill2_kernel      <<<eb,   256, 0, stream>>>(srcv, dstv, ew, rank, dinv, rowptr, edges, nE);

    const int gb = (n + BM - 1) / BM;
    const int nb = (n + 3) / 4;

    // Layer 1: x -> P(H) -> Q
    gemm_kernel<128><<<gb, 256, 0, stream>>>(x, W1, P, n);
    gather_ln_kernel<128, true><<<nb, 256, 0, stream>>>(P, edges, rowptr, dinv, b1, g1, t1, Q, n);

    // Layer 2: Q -> P(H) -> Q
    gemm_kernel<128><<<gb, 256, 0, stream>>>(Q, W2, P, n);
    gather_ln_kernel<128, true><<<nb, 256, 0, stream>>>(P, edges, rowptr, dinv, b2, g2, t2, Q, n);

    // Layer 3: Q -> P(H3, n*64) -> d_out
    gemm_kernel<64><<<gb, 256, 0, stream>>>(Q, W3, P, n);
    gather_ln_kernel<64, false><<<nb, 256, 0, stream>>>(P, edges, rowptr, dinv, b3, g3, t3, (float*)d_out, n);
}

// Round 6
// 354.402 us; speedup vs baseline: 10.2740x; 1.1330x over previous
//
#include <hip/hip_runtime.h>

// ---------------------------------------------------------------------------
// SpatialGCN: 3x (GCNConv -> LayerNorm -> ReLU[except last])
// N=50000, E=800000, dims 128->128->128->64, f32 in/out.
//
// R5 change (from profile: 3x gather_ln = 175us, bytes-bound at 3.6 TB/s on
// the L2-miss path, 187 MB FETCH each): H stored as bf16 (packed RNE in the
// GEMM epilogue) -> gather row 512B -> 256B, logical gather traffic halves.
// Accumulation stays f32; LayerNorm unchanged; final output f32.
// ---------------------------------------------------------------------------

static constexpr int BM = 64;   // rows per GEMM block
static constexpr int KC = 32;   // k-chunk staged in LDS
static constexpr float FXS  = 16777216.0f;        // 2^24
static constexpr float FXSI = 1.0f / 16777216.0f;

__device__ __forceinline__ unsigned short f2bf(float f) {
    unsigned int u = __float_as_uint(f);
    u += 0x7FFFu + ((u >> 16) & 1u);          // round-to-nearest-even
    return (unsigned short)(u >> 16);
}

// ---- Pass A: one u64 atomic per edge -> deg-sum + histogram + rank --------
__global__ __launch_bounds__(256) void edge_pass_kernel(
    const int* __restrict__ dst, const float* __restrict__ ew,
    unsigned long long* __restrict__ packed, int* __restrict__ rank, int nE)
{
    int e = blockIdx.x * 256 + threadIdx.x;
    if (e >= nE) return;
    const int d = dst[e];
    const unsigned long long fx = (unsigned long long)__float2uint_rn(ew[e] * FXS);
    const unsigned long long old = atomicAdd(&packed[d], (1ULL << 40) | fx);
    rank[e] = (int)(old >> 40);
}

// ---- Pass B: dinv from packed + per-block count partials ------------------
__global__ __launch_bounds__(256) void dinv_partial_kernel(
    const unsigned long long* __restrict__ packed, int* __restrict__ partials,
    float* __restrict__ dinv, int n)
{
    const int b = blockIdx.x;
    const int i = b * 256 + threadIdx.x;
    int c = 0;
    if (i < n) {
        const unsigned long long p = packed[i];
        c = (int)(p >> 40);
        const float deg = (float)(p & ((1ULL << 40) - 1)) * FXSI;
        dinv[i] = rsqrtf(deg + 1.0f);       // +1 = self-loop weight
    }
#pragma unroll
    for (int off = 32; off; off >>= 1) c += __shfl_xor(c, off);
    __shared__ int red[4];
    if ((threadIdx.x & 63) == 0) red[threadIdx.x >> 6] = c;
    __syncthreads();
    if (threadIdx.x == 0) partials[b] = red[0] + red[1] + red[2] + red[3];
}

// ---- Pass C: exclusive scan of <=256 block partials -----------------------
__global__ __launch_bounds__(256) void scanp_kernel(
    int* __restrict__ partials, int* __restrict__ rowptr, int n, int nblk)
{
    __shared__ int buf[256];
    const int v = (threadIdx.x < nblk) ? partials[threadIdx.x] : 0;
    buf[threadIdx.x] = v;
    __syncthreads();
    for (int off = 1; off < 256; off <<= 1) {
        const int t = (threadIdx.x >= off) ? buf[threadIdx.x - off] : 0;
        __syncthreads();
        buf[threadIdx.x] += t;
        __syncthreads();
    }
    if (threadIdx.x < nblk) partials[threadIdx.x] = buf[threadIdx.x] - v;  // exclusive
    if (threadIdx.x == 255) rowptr[n] = buf[255];                          // total = E
}

// ---- Pass D: intra-block scan + offset -> rowptr --------------------------
__global__ __launch_bounds__(256) void scanf_kernel(
    const unsigned long long* __restrict__ packed, const int* __restrict__ partials,
    int* __restrict__ rowptr, int n)
{
    __shared__ int buf[256];
    const int b = blockIdx.x;
    const int i = b * 256 + threadIdx.x;
    const int v = (i < n) ? (int)(packed[i] >> 40) : 0;
    buf[threadIdx.x] = v;
    __syncthreads();
    for (int off = 1; off < 256; off <<= 1) {
        const int t = (threadIdx.x >= off) ? buf[threadIdx.x - off] : 0;
        __syncthreads();
        buf[threadIdx.x] += t;
        __syncthreads();
    }
    if (i < n) rowptr[i] = buf[threadIdx.x] - v + partials[b];
}

// ---- Pass E: atomic-free CSR fill -----------------------------------------
__global__ __launch_bounds__(256) void fill2_kernel(
    const int* __restrict__ src, const int* __restrict__ dst,
    const float* __restrict__ ew, const int* __restrict__ rank,
    const float* __restrict__ dinv, const int* __restrict__ rowptr,
    int2* __restrict__ edges, int nE)
{
    int e = blockIdx.x * 256 + threadIdx.x;
    if (e >= nE) return;
    const int s = src[e], d = dst[e];
    const float nrm = dinv[s] * ew[e] * dinv[d];
    edges[rowptr[d] + rank[e]] = make_int2(s, __float_as_int(nrm));
}

// ------ GEMM: H(bf16) = X[n,128](f32) @ W[128,DOUT](f32), RNE pack ---------
template<int DOUT>
__global__ __launch_bounds__(256) void gemm_kernel(
    const float* __restrict__ X, const float* __restrict__ W,
    unsigned short* __restrict__ H, int n)
{
    __shared__ float wl[KC * DOUT];
    __shared__ float xl[BM][132];          // +4 pad: conflict-free b128 reads
    const int tid  = threadIdx.x;
    const int row0 = blockIdx.x * BM;

    for (int i = tid; i < BM * 32; i += 256) {
        const int r = i >> 5, c4 = i & 31;
        const int gr = row0 + r;
        float4 v = make_float4(0.f, 0.f, 0.f, 0.f);
        if (gr < n) v = ((const float4*)(X + (size_t)gr * 128))[c4];
        *(float4*)&xl[r][c4 * 4] = v;
    }

    constexpr int CG  = DOUT / 4;
    constexpr int RT  = 256 / CG;
    constexpr int RPT = BM / RT;
    const int cg = tid % CG;
    const int rt = tid / CG;

    float4 acc[RPT];
#pragma unroll
    for (int r = 0; r < RPT; ++r) acc[r] = make_float4(0.f, 0.f, 0.f, 0.f);

    for (int kc = 0; kc < 128 / KC; ++kc) {
        __syncthreads();
        for (int i = tid; i < KC * CG; i += 256)
            ((float4*)wl)[i] = ((const float4*)(W + (size_t)kc * KC * DOUT))[i];
        __syncthreads();
#pragma unroll
        for (int k4 = 0; k4 < KC / 4; ++k4) {
            float4 xv[RPT];
#pragma unroll
            for (int r = 0; r < RPT; ++r)
                xv[r] = *(const float4*)&xl[rt + RT * r][kc * KC + k4 * 4];
#pragma unroll
            for (int kk = 0; kk < 4; ++kk) {
                const float4 wv = ((const float4*)&wl[(k4 * 4 + kk) * DOUT])[cg];
#pragma unroll
                for (int r = 0; r < RPT; ++r) {
                    const float xs = kk == 0 ? xv[r].x : kk == 1 ? xv[r].y
                                   : kk == 2 ? xv[r].z : xv[r].w;
                    acc[r].x = fmaf(xs, wv.x, acc[r].x);
                    acc[r].y = fmaf(xs, wv.y, acc[r].y);
                    acc[r].z = fmaf(xs, wv.z, acc[r].z);
                    acc[r].w = fmaf(xs, wv.w, acc[r].w);
                }
            }
        }
    }

#pragma unroll
    for (int r = 0; r < RPT; ++r) {
        const int gr = row0 + rt + RT * r;
        if (gr < n) {
            ushort4 hv;
            hv.x = f2bf(acc[r].x); hv.y = f2bf(acc[r].y);
            hv.z = f2bf(acc[r].z); hv.w = f2bf(acc[r].w);
            *(ushort4*)(H + (size_t)gr * DOUT + cg * 4) = hv;   // 8B store
        }
    }
}

// -- gather(bf16 H, f32 acc) + self-loop/bias + LayerNorm(+ReLU), 1 wave/node
template<int D, bool RELU>
__global__ __launch_bounds__(256) void gather_ln_kernel(
    const unsigned short* __restrict__ H, const int2* __restrict__ edges,
    const int* __restrict__ rowptr, const float* __restrict__ dinv,
    const float* __restrict__ bias, const float* __restrict__ g,
    const float* __restrict__ t, float* __restrict__ OUT, int n)
{
    constexpr int PL = D / 64;               // bf16 elems per lane (2 or 1)
    const int lane = threadIdx.x & 63;
    const int node = blockIdx.x * 4 + (threadIdx.x >> 6);
    if (node >= n) return;

    const float di = dinv[node];
    const float sn = di * di;                // self-loop norm = 1/deg
    float acc[PL];
    {
        const unsigned short* hd = H + (size_t)node * D + lane * PL;
        if constexpr (PL == 2) {
            const unsigned int w = *(const unsigned int*)hd;
            acc[0] = fmaf(__uint_as_float(w << 16), sn, bias[lane * 2]);
            acc[1] = fmaf(__uint_as_float(w & 0xFFFF0000u), sn, bias[lane * 2 + 1]);
        } else {
            acc[0] = fmaf(__uint_as_float((unsigned int)hd[0] << 16), sn, bias[lane]);
        }
    }

    const int k0 = rowptr[node], k1 = rowptr[node + 1];
    for (int base = k0; base < k1; base += 64) {
        int2 ed = make_int2(0, 0);
        if (base + lane < k1) ed = edges[base + lane];
        const int cnt = min(64, k1 - base);
        int j = 0;
        for (; j + 4 <= cnt; j += 4) {       // 4 independent gather chains in flight
#pragma unroll
            for (int u = 0; u < 4; ++u) {
                const int   s   = __shfl(ed.x, j + u);
                const float nrm = __int_as_float(__shfl(ed.y, j + u));
                const unsigned short* hs = H + (size_t)s * D + lane * PL;
                if constexpr (PL == 2) {
                    const unsigned int w = *(const unsigned int*)hs;
                    acc[0] = fmaf(__uint_as_float(w << 16), nrm, acc[0]);
                    acc[1] = fmaf(__uint_as_float(w & 0xFFFF0000u), nrm, acc[1]);
                } else {
                    acc[0] = fmaf(__uint_as_float((unsigned int)hs[0] << 16), nrm, acc[0]);
                }
            }
        }
        for (; j < cnt; ++j) {
            const int   s   = __shfl(ed.x, j);
            const float nrm = __int_as_float(__shfl(ed.y, j));
            const unsigned short* hs = H + (size_t)s * D + lane * PL;
            if constexpr (PL == 2) {
                const unsigned int w = *(const unsigned int*)hs;
                acc[0] = fmaf(__uint_as_float(w << 16), nrm, acc[0]);
                acc[1] = fmaf(__uint_as_float(w & 0xFFFF0000u), nrm, acc[1]);
            } else {
                acc[0] = fmaf(__uint_as_float((unsigned int)hs[0] << 16), nrm, acc[0]);
            }
        }
    }

    // LayerNorm across the wave (full row is in wave registers)
    float s1 = 0.f;
#pragma unroll
    for (int i = 0; i < PL; ++i) s1 += acc[i];
#pragma unroll
    for (int off = 32; off; off >>= 1) s1 += __shfl_xor(s1, off);
    const float m = s1 * (1.f / D);
    float s2 = 0.f;
#pragma unroll
    for (int i = 0; i < PL; ++i) { acc[i] -= m; s2 += acc[i] * acc[i]; }
#pragma unroll
    for (int off = 32; off; off >>= 1) s2 += __shfl_xor(s2, off);
    const float rs = rsqrtf(s2 * (1.f / D) + 1e-5f);

    float* o = OUT + (size_t)node * D + lane * PL;
#pragma unroll
    for (int i = 0; i < PL; ++i) {
        float r = fmaf(acc[i] * rs, g[lane * PL + i], t[lane * PL + i]);
        if (RELU) r = fmaxf(r, 0.f);
        o[i] = r;
    }
}

// ---------------------------------------------------------------------------
extern "C" void kernel_launch(void* const* d_in, const int* in_sizes, int n_in,
                              void* d_out, int out_size, void* d_ws, size_t ws_size,
                              hipStream_t stream)
{
    const float* x  = (const float*)d_in[0];
    const int*   ei = (const int*)  d_in[1];
    const float* ew = (const float*)d_in[2];
    const float* W1 = (const float*)d_in[3];
    const float* b1 = (const float*)d_in[4];
    const float* g1 = (const float*)d_in[5];
    const float* t1 = (const float*)d_in[6];
    const float* W2 = (const float*)d_in[7];
    const float* b2 = (const float*)d_in[8];
    const float* g2 = (const float*)d_in[9];
    const float* t2 = (const float*)d_in[10];
    const float* W3 = (const float*)d_in[11];
    const float* b3 = (const float*)d_in[12];
    const float* g3 = (const float*)d_in[13];
    const float* t3 = (const float*)d_in[14];

    const int n  = in_sizes[0] / 128;
    const int nE = in_sizes[1] / 2;
    const int* srcv = ei;           // edge_index[0]
    const int* dstv = ei + nE;      // edge_index[1]

    const size_t na   = ((size_t)n + 63) & ~(size_t)63;
    const int    nblk = (n + 255) / 256;    // scan blocks (<=256 required; 196 here)
    const int    eb   = (nE + 255) / 256;

    // ws: packed[na] u64 | dinv[na] f32 | rowptr[na+64] i32 | partials[256] i32 |
    //     edges[E] int2 | Hb[n*128] bf16 | Q[n*128] f32
    // rank[nE] overlays Hb (free until first GEMM).
    unsigned long long* packed = (unsigned long long*)d_ws;
    float* dinv     = (float*)(packed + na);
    int*   rowptr   = (int*)(dinv + na);
    int*   partials = rowptr + na + 64;
    int2*  edges    = (int2*)(partials + 256);
    unsigned short* Hb = (unsigned short*)(edges + nE);
    float* Q        = (float*)(Hb + (size_t)n * 128);
    int*   rank     = (int*)Hb;

    hipMemsetAsync(packed, 0, na * sizeof(unsigned long long), stream);

    // graph prep (once per call; reused by all 3 layers)
    edge_pass_kernel   <<<eb,   256, 0, stream>>>(dstv, ew, packed, rank, nE);
    dinv_partial_kernel<<<nblk, 256, 0, stream>>>(packed, partials, dinv, n);
    scanp_kernel       <<<1,    256, 0, stream>>>(partials, rowptr, n, nblk);
    scanf_kernel       <<<nblk, 256, 0, stream>>>(packed, partials, rowptr, n);
    fill2_kernel       <<<eb,   256, 0, stream>>>(srcv, dstv, ew, rank, dinv, rowptr, edges, nE);

    const int gb = (n + BM - 1) / BM;
    const int nb = (n + 3) / 4;

    // Layer 1: x -> Hb -> Q
    gemm_kernel<128><<<gb, 256, 0, stream>>>(x, W1, Hb, n);
    gather_ln_kernel<128, true><<<nb, 256, 0, stream>>>(Hb, edges, rowptr, dinv, b1, g1, t1, Q, n);

    // Layer 2: Q -> Hb -> Q
    gemm_kernel<128><<<gb, 256, 0, stream>>>(Q, W2, Hb, n);
    gather_ln_kernel<128, true><<<nb, 256, 0, stream>>>(Hb, edges, rowptr, dinv, b2, g2, t2, Q, n);

    // Layer 3: Q -> Hb(n*64) -> d_out
    gemm_kernel<64><<<gb, 256, 0, stream>>>(Q, W3, Hb, n);
    gather_ln_kernel<64, false><<<nb, 256, 0, stream>>>(Hb, edges, rowptr, dinv, b3, g3, t3, (float*)d_out, n);
}

// Round 7
// 325.874 us; speedup vs baseline: 11.1735x; 1.0875x over previous
//
#include <hip/hip_runtime.h>

// ---------------------------------------------------------------------------
// SpatialGCN: 3x (GCNConv -> LayerNorm -> ReLU[except last])
// N=50000, E=800000, dims 128->128->128->64, f32 in/out.
//
// R6 change (from profile: f32 gemm 115us total, occupancy-bound at 23% of
// the f32 VALU peak): GEMMs moved to bf16 MFMA (16x16x32, f32 accumulate).
//  - x converted to bf16 once; W1/2/3 converted+transposed once (Wt[j][k])
//  - LN outputs of layers 1-2 written as bf16 (feed next GEMM directly)
//  - MFMA gemm: no LDS, no barriers; one wave per 16 rows; W L1-resident
// Fragment layout (m89/m92/m97-verified): A/B lane l -> row/col l&15,
// k = 8*(l>>4)+j contiguous (16B load); C/D col=l&15, row=4*(l>>4)+reg.
// ---------------------------------------------------------------------------

typedef __attribute__((ext_vector_type(8))) short short8;
typedef __attribute__((ext_vector_type(4))) float f32x4;

static constexpr float FXS  = 16777216.0f;        // 2^24
static constexpr float FXSI = 1.0f / 16777216.0f;

__device__ __forceinline__ unsigned short f2bf(float f) {
    unsigned int u = __float_as_uint(f);
    u += 0x7FFFu + ((u >> 16) & 1u);          // round-to-nearest-even
    return (unsigned short)(u >> 16);
}

// ---- Pass A: one u64 atomic per edge -> deg-sum + histogram + rank --------
__global__ __launch_bounds__(256) void edge_pass_kernel(
    const int* __restrict__ dst, const float* __restrict__ ew,
    unsigned long long* __restrict__ packed, int* __restrict__ rank, int nE)
{
    int e = blockIdx.x * 256 + threadIdx.x;
    if (e >= nE) return;
    const int d = dst[e];
    const unsigned long long fx = (unsigned long long)__float2uint_rn(ew[e] * FXS);
    const unsigned long long old = atomicAdd(&packed[d], (1ULL << 40) | fx);
    rank[e] = (int)(old >> 40);
}

// ---- Pass B: dinv from packed + per-block count partials ------------------
__global__ __launch_bounds__(256) void dinv_partial_kernel(
    const unsigned long long* __restrict__ packed, int* __restrict__ partials,
    float* __restrict__ dinv, int n)
{
    const int b = blockIdx.x;
    const int i = b * 256 + threadIdx.x;
    int c = 0;
    if (i < n) {
        const unsigned long long p = packed[i];
        c = (int)(p >> 40);
        const float deg = (float)(p & ((1ULL << 40) - 1)) * FXSI;
        dinv[i] = rsqrtf(deg + 1.0f);       // +1 = self-loop weight
    }
#pragma unroll
    for (int off = 32; off; off >>= 1) c += __shfl_xor(c, off);
    __shared__ int red[4];
    if ((threadIdx.x & 63) == 0) red[threadIdx.x >> 6] = c;
    __syncthreads();
    if (threadIdx.x == 0) partials[b] = red[0] + red[1] + red[2] + red[3];
}

// ---- Pass C: exclusive scan of <=256 block partials -----------------------
__global__ __launch_bounds__(256) void scanp_kernel(
    int* __restrict__ partials, int* __restrict__ rowptr, int n, int nblk)
{
    __shared__ int buf[256];
    const int v = (threadIdx.x < nblk) ? partials[threadIdx.x] : 0;
    buf[threadIdx.x] = v;
    __syncthreads();
    for (int off = 1; off < 256; off <<= 1) {
        const int t = (threadIdx.x >= off) ? buf[threadIdx.x - off] : 0;
        __syncthreads();
        buf[threadIdx.x] += t;
        __syncthreads();
    }
    if (threadIdx.x < nblk) partials[threadIdx.x] = buf[threadIdx.x] - v;  // exclusive
    if (threadIdx.x == 255) rowptr[n] = buf[255];                          // total = E
}

// ---- Pass D: intra-block scan + offset -> rowptr --------------------------
__global__ __launch_bounds__(256) void scanf_kernel(
    const unsigned long long* __restrict__ packed, const int* __restrict__ partials,
    int* __restrict__ rowptr, int n)
{
    __shared__ int buf[256];
    const int b = blockIdx.x;
    const int i = b * 256 + threadIdx.x;
    const int v = (i < n) ? (int)(packed[i] >> 40) : 0;
    buf[threadIdx.x] = v;
    __syncthreads();
    for (int off = 1; off < 256; off <<= 1) {
        const int t = (threadIdx.x >= off) ? buf[threadIdx.x - off] : 0;
        __syncthreads();
        buf[threadIdx.x] += t;
        __syncthreads();
    }
    if (i < n) rowptr[i] = buf[threadIdx.x] - v + partials[b];
}

// ---- Pass E: atomic-free CSR fill -----------------------------------------
__global__ __launch_bounds__(256) void fill2_kernel(
    const int* __restrict__ src, const int* __restrict__ dst,
    const float* __restrict__ ew, const int* __restrict__ rank,
    const float* __restrict__ dinv, const int* __restrict__ rowptr,
    int2* __restrict__ edges, int nE)
{
    int e = blockIdx.x * 256 + threadIdx.x;
    if (e >= nE) return;
    const int s = src[e], d = dst[e];
    const float nrm = dinv[s] * ew[e] * dinv[d];
    edges[rowptr[d] + rank[e]] = make_int2(s, __float_as_int(nrm));
}

// ---- converts: x -> bf16; W -> bf16 transposed ----------------------------
__global__ __launch_bounds__(256) void xconv_kernel(
    const float* __restrict__ X, unsigned short* __restrict__ Xb, int total4)
{
    int i = blockIdx.x * 256 + threadIdx.x;
    if (i >= total4) return;
    const float4 v = ((const float4*)X)[i];
    ushort4 o;
    o.x = f2bf(v.x); o.y = f2bf(v.y); o.z = f2bf(v.z); o.w = f2bf(v.w);
    ((ushort4*)Xb)[i] = o;
}

__global__ __launch_bounds__(256) void wconv_kernel(
    const float* __restrict__ W1, const float* __restrict__ W2,
    const float* __restrict__ W3, unsigned short* __restrict__ Wt1,
    unsigned short* __restrict__ Wt2, unsigned short* __restrict__ Wt3)
{
    int i = blockIdx.x * 256 + threadIdx.x;
    if (i < 16384) {                    // Wt1[128][128] = W1^T
        const int j = i >> 7, k = i & 127;
        Wt1[i] = f2bf(W1[k * 128 + j]);
    } else if (i < 32768) {             // Wt2[128][128] = W2^T
        const int q = i - 16384, j = q >> 7, k = q & 127;
        Wt2[q] = f2bf(W2[k * 128 + j]);
    } else if (i < 40960) {             // Wt3[64][128] = W3^T
        const int q = i - 32768, j = q >> 7, k = q & 127;
        Wt3[q] = f2bf(W3[k * 64 + j]);
    }
}

// ---- MFMA GEMM: H[n][DOUT] (bf16) = Xb[n][128] @ Wt^T, one wave / 16 rows --
template<int DOUT>
__global__ __launch_bounds__(256) void gemm_mfma_kernel(
    const unsigned short* __restrict__ Xb,   // [n][128] bf16
    const unsigned short* __restrict__ Wt,   // [DOUT][128] bf16 (= W^T)
    unsigned short* __restrict__ H, int n)   // [n][DOUT] bf16
{
    const int wave = threadIdx.x >> 6;
    const int lane = threadIdx.x & 63;
    const int row0 = (blockIdx.x * 4 + wave) * 16;
    if (row0 >= n) return;
    const int lr = lane & 15;            // A row / B col within tile
    const int lk = (lane >> 4) * 8;      // k-offset within 32-wide k-step

    constexpr int NCT = DOUT / 16;
    f32x4 acc[NCT];
#pragma unroll
    for (int c = 0; c < NCT; ++c) acc[c] = (f32x4){0.f, 0.f, 0.f, 0.f};

    const int arow = row0 + lr;
    const bool rv = arow < n;
    short8 afrag[4];
#pragma unroll
    for (int ks = 0; ks < 4; ++ks)
        afrag[ks] = rv ? *(const short8*)(Xb + (size_t)arow * 128 + ks * 32 + lk)
                       : (short8){0, 0, 0, 0, 0, 0, 0, 0};

#pragma unroll
    for (int c = 0; c < NCT; ++c) {
        const unsigned short* wp = Wt + (size_t)(c * 16 + lr) * 128 + lk;
#pragma unroll
        for (int ks = 0; ks < 4; ++ks) {
            const short8 bfrag = *(const short8*)(wp + ks * 32);
            acc[c] = __builtin_amdgcn_mfma_f32_16x16x32_bf16(afrag[ks], bfrag, acc[c], 0, 0, 0);
        }
    }

    const int orow0 = row0 + (lane >> 4) * 4;   // C/D: row = 4*(lane>>4)+r
#pragma unroll
    for (int c = 0; c < NCT; ++c) {
#pragma unroll
        for (int r = 0; r < 4; ++r) {
            const int orow = orow0 + r;
            if (orow < n) H[(size_t)orow * DOUT + c * 16 + lr] = f2bf(acc[c][r]);
        }
    }
}

// -- gather(bf16 H, f32 acc) + self-loop/bias + LayerNorm(+ReLU), 1 wave/node
// OB16: write output as packed bf16 (feeds next layer's MFMA GEMM)
template<int D, bool RELU, bool OB16>
__global__ __launch_bounds__(256) void gather_ln_kernel(
    const unsigned short* __restrict__ H, const int2* __restrict__ edges,
    const int* __restrict__ rowptr, const float* __restrict__ dinv,
    const float* __restrict__ bias, const float* __restrict__ g,
    const float* __restrict__ t, void* __restrict__ OUT, int n)
{
    constexpr int PL = D / 64;               // bf16 elems per lane (2 or 1)
    const int lane = threadIdx.x & 63;
    const int node = blockIdx.x * 4 + (threadIdx.x >> 6);
    if (node >= n) return;

    const float di = dinv[node];
    const float sn = di * di;                // self-loop norm = 1/deg
    float acc[PL];
    {
        const unsigned short* hd = H + (size_t)node * D + lane * PL;
        if constexpr (PL == 2) {
            const unsigned int w = *(const unsigned int*)hd;
            acc[0] = fmaf(__uint_as_float(w << 16), sn, bias[lane * 2]);
            acc[1] = fmaf(__uint_as_float(w & 0xFFFF0000u), sn, bias[lane * 2 + 1]);
        } else {
            acc[0] = fmaf(__uint_as_float((unsigned int)hd[0] << 16), sn, bias[lane]);
        }
    }

    const int k0 = rowptr[node], k1 = rowptr[node + 1];
    for (int base = k0; base < k1; base += 64) {
        int2 ed = make_int2(0, 0);
        if (base + lane < k1) ed = edges[base + lane];
        const int cnt = min(64, k1 - base);
        int j = 0;
        for (; j + 4 <= cnt; j += 4) {       // 4 independent gather chains in flight
#pragma unroll
            for (int u = 0; u < 4; ++u) {
                const int   s   = __shfl(ed.x, j + u);
                const float nrm = __int_as_float(__shfl(ed.y, j + u));
                const unsigned short* hs = H + (size_t)s * D + lane * PL;
                if constexpr (PL == 2) {
                    const unsigned int w = *(const unsigned int*)hs;
                    acc[0] = fmaf(__uint_as_float(w << 16), nrm, acc[0]);
                    acc[1] = fmaf(__uint_as_float(w & 0xFFFF0000u), nrm, acc[1]);
                } else {
                    acc[0] = fmaf(__uint_as_float((unsigned int)hs[0] << 16), nrm, acc[0]);
                }
            }
        }
        for (; j < cnt; ++j) {
            const int   s   = __shfl(ed.x, j);
            const float nrm = __int_as_float(__shfl(ed.y, j));
            const unsigned short* hs = H + (size_t)s * D + lane * PL;
            if constexpr (PL == 2) {
                const unsigned int w = *(const unsigned int*)hs;
                acc[0] = fmaf(__uint_as_float(w << 16), nrm, acc[0]);
                acc[1] = fmaf(__uint_as_float(w & 0xFFFF0000u), nrm, acc[1]);
            } else {
                acc[0] = fmaf(__uint_as_float((unsigned int)hs[0] << 16), nrm, acc[0]);
            }
        }
    }

    // LayerNorm across the wave (full row is in wave registers)
    float s1 = 0.f;
#pragma unroll
    for (int i = 0; i < PL; ++i) s1 += acc[i];
#pragma unroll
    for (int off = 32; off; off >>= 1) s1 += __shfl_xor(s1, off);
    const float m = s1 * (1.f / D);
    float s2 = 0.f;
#pragma unroll
    for (int i = 0; i < PL; ++i) { acc[i] -= m; s2 += acc[i] * acc[i]; }
#pragma unroll
    for (int off = 32; off; off >>= 1) s2 += __shfl_xor(s2, off);
    const float rs = rsqrtf(s2 * (1.f / D) + 1e-5f);

    float r[PL];
#pragma unroll
    for (int i = 0; i < PL; ++i) {
        r[i] = fmaf(acc[i] * rs, g[lane * PL + i], t[lane * PL + i]);
        if (RELU) r[i] = fmaxf(r[i], 0.f);
    }
    if constexpr (OB16) {
        static_assert(PL == 2, "bf16 output path assumes D=128");
        const unsigned int w = (unsigned int)f2bf(r[0]) | ((unsigned int)f2bf(r[1]) << 16);
        ((unsigned int*)OUT)[(size_t)node * (D / 2) + lane] = w;
    } else {
        float* o = (float*)OUT + (size_t)node * D + lane * PL;
#pragma unroll
        for (int i = 0; i < PL; ++i) o[i] = r[i];
    }
}

// ---------------------------------------------------------------------------
extern "C" void kernel_launch(void* const* d_in, const int* in_sizes, int n_in,
                              void* d_out, int out_size, void* d_ws, size_t ws_size,
                              hipStream_t stream)
{
    const float* x  = (const float*)d_in[0];
    const int*   ei = (const int*)  d_in[1];
    const float* ew = (const float*)d_in[2];
    const float* W1 = (const float*)d_in[3];
    const float* b1 = (const float*)d_in[4];
    const float* g1 = (const float*)d_in[5];
    const float* t1 = (const float*)d_in[6];
    const float* W2 = (const float*)d_in[7];
    const float* b2 = (const float*)d_in[8];
    const float* g2 = (const float*)d_in[9];
    const float* t2 = (const float*)d_in[10];
    const float* W3 = (const float*)d_in[11];
    const float* b3 = (const float*)d_in[12];
    const float* g3 = (const float*)d_in[13];
    const float* t3 = (const float*)d_in[14];

    const int n  = in_sizes[0] / 128;
    const int nE = in_sizes[1] / 2;
    const int* srcv = ei;           // edge_index[0]
    const int* dstv = ei + nE;      // edge_index[1]

    const size_t na   = ((size_t)n + 63) & ~(size_t)63;
    const int    nblk = (n + 255) / 256;    // scan blocks (<=256 required; 196 here)
    const int    eb   = (nE + 255) / 256;

    // ws: packed[na] u64 | dinv[na] f32 | rowptr[na+64] i32 | partials[256] i32 |
    //     edges[E] int2 | Hb[n*128] bf16 | Qb[n*128] bf16 | xb[n*128] bf16 |
    //     Wt1[16384] bf16 | Wt2[16384] bf16 | Wt3[8192] bf16
    // rank[nE] overlays Hb (free until first GEMM).
    unsigned long long* packed = (unsigned long long*)d_ws;
    float* dinv     = (float*)(packed + na);
    int*   rowptr   = (int*)(dinv + na);
    int*   partials = rowptr + na + 64;
    int2*  edges    = (int2*)(partials + 256);
    unsigned short* Hb  = (unsigned short*)(edges + nE);
    unsigned short* Qb  = Hb + (size_t)n * 128;
    unsigned short* xb  = Qb + (size_t)n * 128;
    unsigned short* Wt1 = xb + (size_t)n * 128;
    unsigned short* Wt2 = Wt1 + 16384;
    unsigned short* Wt3 = Wt2 + 16384;
    int* rank = (int*)Hb;

    hipMemsetAsync(packed, 0, na * sizeof(unsigned long long), stream);

    // graph prep (once per call; reused by all 3 layers)
    edge_pass_kernel   <<<eb,   256, 0, stream>>>(dstv, ew, packed, rank, nE);
    dinv_partial_kernel<<<nblk, 256, 0, stream>>>(packed, partials, dinv, n);
    scanp_kernel       <<<1,    256, 0, stream>>>(partials, rowptr, n, nblk);
    scanf_kernel       <<<nblk, 256, 0, stream>>>(packed, partials, rowptr, n);
    fill2_kernel       <<<eb,   256, 0, stream>>>(srcv, dstv, ew, rank, dinv, rowptr, edges, nE);

    // input converts (x once; W once)
    xconv_kernel<<<(n * 32 + 255) / 256, 256, 0, stream>>>(x, xb, n * 32);
    wconv_kernel<<<160, 256, 0, stream>>>(W1, W2, W3, Wt1, Wt2, Wt3);

    const int gb = (n + 63) / 64;           // 16 rows/wave * 4 waves/block
    const int nb = (n + 3) / 4;

    // Layer 1: xb -> Hb -> Qb
    gemm_mfma_kernel<128><<<gb, 256, 0, stream>>>(xb, Wt1, Hb, n);
    gather_ln_kernel<128, true, true><<<nb, 256, 0, stream>>>(Hb, edges, rowptr, dinv, b1, g1, t1, Qb, n);

    // Layer 2: Qb -> Hb -> Qb (gather reads only Hb/edges; safe in-place Qb)
    gemm_mfma_kernel<128><<<gb, 256, 0, stream>>>(Qb, Wt2, Hb, n);
    gather_ln_kernel<128, true, true><<<nb, 256, 0, stream>>>(Hb, edges, rowptr, dinv, b2, g2, t2, Qb, n);

    // Layer 3: Qb -> Hb(n*64) -> d_out (f32)
    gemm_mfma_kernel<64><<<gb, 256, 0, stream>>>(Qb, Wt3, Hb, n);
    gather_ln_kernel<64, false, false><<<nb, 256, 0, stream>>>(Hb, edges, rowptr, dinv, b3, g3, t3, d_out, n);
}

// Round 9
// 301.971 us; speedup vs baseline: 12.0579x; 1.0792x over previous
//
#include <hip/hip_runtime.h>

// ---------------------------------------------------------------------------
// SpatialGCN: 3x (GCNConv -> LayerNorm -> ReLU[except last])
// N=50000, E=800000, dims 128->128->128->64, f32 in/out.
//
// R7 changes (resubmitted R8; never ran due to GPU timeout):
//  - gather: one 16-lane group per node (8-lane for D=64), dwordx4 row loads
//    (4x fewer loads, 8x fewer shfl, 4-8 independent nodes in flight per wave)
//  - prep fusion: edge_pass + xconv + wconv in ONE kernel (disjoint block
//    ranges) -- converts ride under the atomic-rate-bound edge pass
// ---------------------------------------------------------------------------

typedef __attribute__((ext_vector_type(8))) short short8;
typedef __attribute__((ext_vector_type(4))) float f32x4;

static constexpr float FXS  = 16777216.0f;        // 2^24
static constexpr float FXSI = 1.0f / 16777216.0f;

__device__ __forceinline__ unsigned short f2bf(float f) {
    unsigned int u = __float_as_uint(f);
    u += 0x7FFFu + ((u >> 16) & 1u);          // round-to-nearest-even
    return (unsigned short)(u >> 16);
}
__device__ __forceinline__ float bflo(unsigned int w) { return __uint_as_float(w << 16); }
__device__ __forceinline__ float bfhi(unsigned int w) { return __uint_as_float(w & 0xFFFF0000u); }

// ---- fused prep: edge histogram/deg/rank + x->bf16 + W->bf16^T ------------
__global__ __launch_bounds__(256) void prep_kernel(
    const int* __restrict__ dst, const float* __restrict__ ew,
    unsigned long long* __restrict__ packed, int* __restrict__ rank, int nE, int eb,
    const float* __restrict__ X, unsigned short* __restrict__ Xb, int total4, int xbk,
    const float* __restrict__ W1, const float* __restrict__ W2,
    const float* __restrict__ W3, unsigned short* __restrict__ Wt1,
    unsigned short* __restrict__ Wt2, unsigned short* __restrict__ Wt3)
{
    const int b = blockIdx.x;
    if (b < eb) {                           // --- edge pass (atomic-rate-bound)
        const int e = b * 256 + threadIdx.x;
        if (e < nE) {
            const int d = dst[e];
            const unsigned long long fx = (unsigned long long)__float2uint_rn(ew[e] * FXS);
            const unsigned long long old = atomicAdd(&packed[d], (1ULL << 40) | fx);
            rank[e] = (int)(old >> 40);
        }
    } else if (b < eb + xbk) {              // --- x -> bf16 (BW-bound, rides along)
        const int i = (b - eb) * 256 + threadIdx.x;
        if (i < total4) {
            const float4 v = ((const float4*)X)[i];
            ushort4 o;
            o.x = f2bf(v.x); o.y = f2bf(v.y); o.z = f2bf(v.z); o.w = f2bf(v.w);
            ((ushort4*)Xb)[i] = o;
        }
    } else {                                // --- W -> bf16 transposed (tiny)
        const int i = (b - eb - xbk) * 256 + threadIdx.x;
        if (i < 16384) {                    // Wt1[128][128] = W1^T
            const int j = i >> 7, k = i & 127;
            Wt1[i] = f2bf(W1[k * 128 + j]);
        } else if (i < 32768) {             // Wt2
            const int q = i - 16384, j = q >> 7, k = q & 127;
            Wt2[q] = f2bf(W2[k * 128 + j]);
        } else if (i < 40960) {             // Wt3[64][128] = W3^T
            const int q = i - 32768, j = q >> 7, k = q & 127;
            Wt3[q] = f2bf(W3[k * 64 + j]);
        }
    }
}

// ---- dinv from packed + per-block count partials --------------------------
__global__ __launch_bounds__(256) void dinv_partial_kernel(
    const unsigned long long* __restrict__ packed, int* __restrict__ partials,
    float* __restrict__ dinv, int n)
{
    const int b = blockIdx.x;
    const int i = b * 256 + threadIdx.x;
    int c = 0;
    if (i < n) {
        const unsigned long long p = packed[i];
        c = (int)(p >> 40);
        const float deg = (float)(p & ((1ULL << 40) - 1)) * FXSI;
        dinv[i] = rsqrtf(deg + 1.0f);       // +1 = self-loop weight
    }
#pragma unroll
    for (int off = 32; off; off >>= 1) c += __shfl_xor(c, off);
    __shared__ int red[4];
    if ((threadIdx.x & 63) == 0) red[threadIdx.x >> 6] = c;
    __syncthreads();
    if (threadIdx.x == 0) partials[b] = red[0] + red[1] + red[2] + red[3];
}

// ---- exclusive scan of <=256 block partials -------------------------------
__global__ __launch_bounds__(256) void scanp_kernel(
    int* __restrict__ partials, int* __restrict__ rowptr, int n, int nblk)
{
    __shared__ int buf[256];
    const int v = (threadIdx.x < nblk) ? partials[threadIdx.x] : 0;
    buf[threadIdx.x] = v;
    __syncthreads();
    for (int off = 1; off < 256; off <<= 1) {
        const int t = (threadIdx.x >= off) ? buf[threadIdx.x - off] : 0;
        __syncthreads();
        buf[threadIdx.x] += t;
        __syncthreads();
    }
    if (threadIdx.x < nblk) partials[threadIdx.x] = buf[threadIdx.x] - v;  // exclusive
    if (threadIdx.x == 255) rowptr[n] = buf[255];                          // total = E
}

// ---- intra-block scan + offset -> rowptr ----------------------------------
__global__ __launch_bounds__(256) void scanf_kernel(
    const unsigned long long* __restrict__ packed, const int* __restrict__ partials,
    int* __restrict__ rowptr, int n)
{
    __shared__ int buf[256];
    const int b = blockIdx.x;
    const int i = b * 256 + threadIdx.x;
    const int v = (i < n) ? (int)(packed[i] >> 40) : 0;
    buf[threadIdx.x] = v;
    __syncthreads();
    for (int off = 1; off < 256; off <<= 1) {
        const int t = (threadIdx.x >= off) ? buf[threadIdx.x - off] : 0;
        __syncthreads();
        buf[threadIdx.x] += t;
        __syncthreads();
    }
    if (i < n) rowptr[i] = buf[threadIdx.x] - v + partials[b];
}

// ---- atomic-free CSR fill -------------------------------------------------
__global__ __launch_bounds__(256) void fill2_kernel(
    const int* __restrict__ src, const int* __restrict__ dst,
    const float* __restrict__ ew, const int* __restrict__ rank,
    const float* __restrict__ dinv, const int* __restrict__ rowptr,
    int2* __restrict__ edges, int nE)
{
    int e = blockIdx.x * 256 + threadIdx.x;
    if (e >= nE) return;
    const int s = src[e], d = dst[e];
    const float nrm = dinv[s] * ew[e] * dinv[d];
    edges[rowptr[d] + rank[e]] = make_int2(s, __float_as_int(nrm));
}

// ---- MFMA GEMM: H[n][DOUT] (bf16) = Xb[n][128] @ Wt^T, one wave / 16 rows --
template<int DOUT>
__global__ __launch_bounds__(256) void gemm_mfma_kernel(
    const unsigned short* __restrict__ Xb,   // [n][128] bf16
    const unsigned short* __restrict__ Wt,   // [DOUT][128] bf16 (= W^T)
    unsigned short* __restrict__ H, int n)   // [n][DOUT] bf16
{
    const int wave = threadIdx.x >> 6;
    const int lane = threadIdx.x & 63;
    const int row0 = (blockIdx.x * 4 + wave) * 16;
    if (row0 >= n) return;
    const int lr = lane & 15;            // A row / B col within tile
    const int lk = (lane >> 4) * 8;      // k-offset within 32-wide k-step

    constexpr int NCT = DOUT / 16;
    f32x4 acc[NCT];
#pragma unroll
    for (int c = 0; c < NCT; ++c) acc[c] = (f32x4){0.f, 0.f, 0.f, 0.f};

    const int arow = row0 + lr;
    const bool rv = arow < n;
    short8 afrag[4];
#pragma unroll
    for (int ks = 0; ks < 4; ++ks)
        afrag[ks] = rv ? *(const short8*)(Xb + (size_t)arow * 128 + ks * 32 + lk)
                       : (short8){0, 0, 0, 0, 0, 0, 0, 0};

#pragma unroll
    for (int c = 0; c < NCT; ++c) {
        const unsigned short* wp = Wt + (size_t)(c * 16 + lr) * 128 + lk;
#pragma unroll
        for (int ks = 0; ks < 4; ++ks) {
            const short8 bfrag = *(const short8*)(wp + ks * 32);
            acc[c] = __builtin_amdgcn_mfma_f32_16x16x32_bf16(afrag[ks], bfrag, acc[c], 0, 0, 0);
        }
    }

    const int orow0 = row0 + (lane >> 4) * 4;   // C/D: row = 4*(lane>>4)+r
#pragma unroll
    for (int c = 0; c < NCT; ++c) {
#pragma unroll
        for (int r = 0; r < 4; ++r) {
            const int orow = orow0 + r;
            if (orow < n) H[(size_t)orow * DOUT + c * 16 + lr] = f2bf(acc[c][r]);
        }
    }
}

// -- gather + self-loop/bias + LayerNorm(+ReLU): one GS-lane group per node --
// GS = D/8 lanes per node; each lane owns 8 bf16 (one dwordx4 per edge-row).
template<int D, bool RELU, bool OB16>
__global__ __launch_bounds__(256) void gather_ln_kernel(
    const unsigned short* __restrict__ H, const int2* __restrict__ edges,
    const int* __restrict__ rowptr, const float* __restrict__ dinv,
    const float* __restrict__ bias, const float* __restrict__ g,
    const float* __restrict__ t, void* __restrict__ OUT, int n)
{
    constexpr int GS  = D / 8;           // lanes per node (16 or 8)
    constexpr int NPW = 64 / GS;         // nodes per wave (4 or 8)
    const int lane = threadIdx.x & 63;
    const int wave = threadIdx.x >> 6;
    const int L    = lane & (GS - 1);    // lane within group
    const int gb0  = lane & ~(GS - 1);   // group's base lane (abs, wave-wide)
    const int node = (blockIdx.x * 4 + wave) * NPW + (lane >> (GS == 16 ? 4 : 3));
    if (node >= n) return;

    const float di = dinv[node];
    const float sn = di * di;            // self-loop norm = 1/deg
    float acc[8];
    {
        const uint4 w = *(const uint4*)(H + (size_t)node * D + L * 8);
        const float4 b0 = *(const float4*)(bias + L * 8);
        const float4 b1 = *(const float4*)(bias + L * 8 + 4);
        acc[0] = fmaf(bflo(w.x), sn, b0.x); acc[1] = fmaf(bfhi(w.x), sn, b0.y);
        acc[2] = fmaf(bflo(w.y), sn, b0.z); acc[3] = fmaf(bfhi(w.y), sn, b0.w);
        acc[4] = fmaf(bflo(w.z), sn, b1.x); acc[5] = fmaf(bfhi(w.z), sn, b1.y);
        acc[6] = fmaf(bflo(w.w), sn, b1.z); acc[7] = fmaf(bfhi(w.w), sn, b1.w);
    }

    const int k0 = rowptr[node], k1 = rowptr[node + 1];
    for (int base = k0; base < k1; base += GS) {
        int2 ed = make_int2(0, 0);
        if (base + L < k1) ed = edges[base + L];
        const int cnt = min(GS, k1 - base);
        int j = 0;
        for (; j + 2 <= cnt; j += 2) {   // 2 row-loads in flight per group
            const int   s0 = __shfl(ed.x, gb0 + j);
            const int   s1 = __shfl(ed.x, gb0 + j + 1);
            const float n0 = __int_as_float(__shfl(ed.y, gb0 + j));
            const float n1 = __int_as_float(__shfl(ed.y, gb0 + j + 1));
            const uint4 w0 = *(const uint4*)(H + (size_t)s0 * D + L * 8);
            const uint4 w1 = *(const uint4*)(H + (size_t)s1 * D + L * 8);
            acc[0] = fmaf(bflo(w0.x), n0, acc[0]); acc[1] = fmaf(bfhi(w0.x), n0, acc[1]);
            acc[2] = fmaf(bflo(w0.y), n0, acc[2]); acc[3] = fmaf(bfhi(w0.y), n0, acc[3]);
            acc[4] = fmaf(bflo(w0.z), n0, acc[4]); acc[5] = fmaf(bfhi(w0.z), n0, acc[5]);
            acc[6] = fmaf(bflo(w0.w), n0, acc[6]); acc[7] = fmaf(bfhi(w0.w), n0, acc[7]);
            acc[0] = fmaf(bflo(w1.x), n1, acc[0]); acc[1] = fmaf(bfhi(w1.x), n1, acc[1]);
            acc[2] = fmaf(bflo(w1.y), n1, acc[2]); acc[3] = fmaf(bfhi(w1.y), n1, acc[3]);
            acc[4] = fmaf(bflo(w1.z), n1, acc[4]); acc[5] = fmaf(bfhi(w1.z), n1, acc[5]);
            acc[6] = fmaf(bflo(w1.w), n1, acc[6]); acc[7] = fmaf(bfhi(w1.w), n1, acc[7]);
        }
        if (j < cnt) {
            const int   s0 = __shfl(ed.x, gb0 + j);
            const float n0 = __int_as_float(__shfl(ed.y, gb0 + j));
            const uint4 w0 = *(const uint4*)(H + (size_t)s0 * D + L * 8);
            acc[0] = fmaf(bflo(w0.x), n0, acc[0]); acc[1] = fmaf(bfhi(w0.x), n0, acc[1]);
            acc[2] = fmaf(bflo(w0.y), n0, acc[2]); acc[3] = fmaf(bfhi(w0.y), n0, acc[3]);
            acc[4] = fmaf(bflo(w0.z), n0, acc[4]); acc[5] = fmaf(bfhi(w0.z), n0, acc[5]);
            acc[6] = fmaf(bflo(w0.w), n0, acc[6]); acc[7] = fmaf(bfhi(w0.w), n0, acc[7]);
        }
    }

    // LayerNorm across the GS-lane group (full row in group registers)
    float s1 = 0.f;
#pragma unroll
    for (int i = 0; i < 8; ++i) s1 += acc[i];
#pragma unroll
    for (int off = GS / 2; off; off >>= 1) s1 += __shfl_xor(s1, off);
    const float m = s1 * (1.f / D);
    float s2 = 0.f;
#pragma unroll
    for (int i = 0; i < 8; ++i) { acc[i] -= m; s2 += acc[i] * acc[i]; }
#pragma unroll
    for (int off = GS / 2; off; off >>= 1) s2 += __shfl_xor(s2, off);
    const float rs = rsqrtf(s2 * (1.f / D) + 1e-5f);

    const float4 g0 = *(const float4*)(g + L * 8), g1 = *(const float4*)(g + L * 8 + 4);
    const float4 t0 = *(const float4*)(t + L * 8), t1 = *(const float4*)(t + L * 8 + 4);
    float r[8];
    r[0] = fmaf(acc[0] * rs, g0.x, t0.x); r[1] = fmaf(acc[1] * rs, g0.y, t0.y);
    r[2] = fmaf(acc[2] * rs, g0.z, t0.z); r[3] = fmaf(acc[3] * rs, g0.w, t0.w);
    r[4] = fmaf(acc[4] * rs, g1.x, t1.x); r[5] = fmaf(acc[5] * rs, g1.y, t1.y);
    r[6] = fmaf(acc[6] * rs, g1.z, t1.z); r[7] = fmaf(acc[7] * rs, g1.w, t1.w);
    if (RELU) {
#pragma unroll
        for (int i = 0; i < 8; ++i) r[i] = fmaxf(r[i], 0.f);
    }

    if constexpr (OB16) {
        uint4 o;
        o.x = (unsigned int)f2bf(r[0]) | ((unsigned int)f2bf(r[1]) << 16);
        o.y = (unsigned int)f2bf(r[2]) | ((unsigned int)f2bf(r[3]) << 16);
        o.z = (unsigned int)f2bf(r[4]) | ((unsigned int)f2bf(r[5]) << 16);
        o.w = (unsigned int)f2bf(r[6]) | ((unsigned int)f2bf(r[7]) << 16);
        *(uint4*)((unsigned short*)OUT + (size_t)node * D + L * 8) = o;
    } else {
        float* o = (float*)OUT + (size_t)node * D + L * 8;
        *(float4*)o       = make_float4(r[0], r[1], r[2], r[3]);
        *(float4*)(o + 4) = make_float4(r[4], r[5], r[6], r[7]);
    }
}

// ---------------------------------------------------------------------------
extern "C" void kernel_launch(void* const* d_in, const int* in_sizes, int n_in,
                              void* d_out, int out_size, void* d_ws, size_t ws_size,
                              hipStream_t stream)
{
    const float* x  = (const float*)d_in[0];
    const int*   ei = (const int*)  d_in[1];
    const float* ew = (const float*)d_in[2];
    const float* W1 = (const float*)d_in[3];
    const float* b1 = (const float*)d_in[4];
    const float* g1 = (const float*)d_in[5];
    const float* t1 = (const float*)d_in[6];
    const float* W2 = (const float*)d_in[7];
    const float* b2 = (const float*)d_in[8];
    const float* g2 = (const float*)d_in[9];
    const float* t2 = (const float*)d_in[10];
    const float* W3 = (const float*)d_in[11];
    const float* b3 = (const float*)d_in[12];
    const float* g3 = (const float*)d_in[13];
    const float* t3 = (const float*)d_in[14];

    const int n  = in_sizes[0] / 128;
    const int nE = in_sizes[1] / 2;
    const int* srcv = ei;           // edge_index[0]
    const int* dstv = ei + nE;      // edge_index[1]

    const size_t na   = ((size_t)n + 63) & ~(size_t)63;
    const int    nblk = (n + 255) / 256;    // scan blocks (<=256 required; 196 here)
    const int    eb   = (nE + 255) / 256;
    const int    xbk  = (n * 32 + 255) / 256;

    // ws: packed[na] u64 | dinv[na] f32 | rowptr[na+64] i32 | partials[256] i32 |
    //     edges[E] int2 | Hb[n*128] bf16 | Qb[n*128] bf16 | xb[n*128] bf16 |
    //     Wt1/Wt2/Wt3 bf16.  rank[nE] overlays Hb (free until first GEMM).
    unsigned long long* packed = (unsigned long long*)d_ws;
    float* dinv     = (float*)(packed + na);
    int*   rowptr   = (int*)(dinv + na);
    int*   partials = rowptr + na + 64;
    int2*  edges    = (int2*)(partials + 256);
    unsigned short* Hb  = (unsigned short*)(edges + nE);
    unsigned short* Qb  = Hb + (size_t)n * 128;
    unsigned short* xb  = Qb + (size_t)n * 128;
    unsigned short* Wt1 = xb + (size_t)n * 128;
    unsigned short* Wt2 = Wt1 + 16384;
    unsigned short* Wt3 = Wt2 + 16384;
    int* rank = (int*)Hb;

    hipMemsetAsync(packed, 0, na * sizeof(unsigned long long), stream);

    // fused prep: edge pass + x/W converts (disjoint block ranges)
    prep_kernel<<<eb + xbk + 160, 256, 0, stream>>>(
        dstv, ew, packed, rank, nE, eb,
        x, xb, n * 32, xbk, W1, W2, W3, Wt1, Wt2, Wt3);
    dinv_partial_kernel<<<nblk, 256, 0, stream>>>(packed, partials, dinv, n);
    scanp_kernel       <<<1,    256, 0, stream>>>(partials, rowptr, n, nblk);
    scanf_kernel       <<<nblk, 256, 0, stream>>>(packed, partials, rowptr, n);
    fill2_kernel       <<<eb,   256, 0, stream>>>(srcv, dstv, ew, rank, dinv, rowptr, edges, nE);

    const int gb   = (n + 63) / 64;         // gemm: 16 rows/wave * 4 waves
    const int nbA  = (n + 15) / 16;         // gather D=128: 16 nodes/block
    const int nbB  = (n + 31) / 32;         // gather D=64:  32 nodes/block

    // Layer 1: xb -> Hb -> Qb
    gemm_mfma_kernel<128><<<gb, 256, 0, stream>>>(xb, Wt1, Hb, n);
    gather_ln_kernel<128, true, true><<<nbA, 256, 0, stream>>>(Hb, edges, rowptr, dinv, b1, g1, t1, Qb, n);

    // Layer 2: Qb -> Hb -> Qb
    gemm_mfma_kernel<128><<<gb, 256, 0, stream>>>(Qb, Wt2, Hb, n);
    gather_ln_kernel<128, true, true><<<nbA, 256, 0, stream>>>(Hb, edges, rowptr, dinv, b2, g2, t2, Qb, n);

    // Layer 3: Qb -> Hb(n*64) -> d_out (f32)
    gemm_mfma_kernel<64><<<gb, 256, 0, stream>>>(Qb, Wt3, Hb, n);
    gather_ln_kernel<64, false, false><<<nbB, 256, 0, stream>>>(Hb, edges, rowptr, dinv, b3, g3, t3, d_out, n);
}

// Round 10
// 298.775 us; speedup vs baseline: 12.1869x; 1.0107x over previous
//
#include <hip/hip_runtime.h>

// ---------------------------------------------------------------------------
// SpatialGCN: 3x (GCNConv -> LayerNorm -> ReLU[except last])
// N=50000, E=800000, dims 128->128->128->64, f32 in/out.
//
// R9 changes (profile: prep 45us, latency-bound on 1 outstanding atomic/lane):
//  - edge pass batched x4: 4 independent u64 atomics in flight per thread
//  - fill2 fused with layer-1 GEMM (disjoint block ranges, both ready after
//    scanf): scattered-write latency hides under MFMA compute
//    NOTE: rank[] therefore overlays Qb (not Hb) -- fill reads rank while
//    gemm blocks write Hb concurrently; Qb is untouched until gather1.
//  - gather edge loop unrolled x4 (4 row-loads in flight per lane-group)
// ---------------------------------------------------------------------------

typedef __attribute__((ext_vector_type(8))) short short8;
typedef __attribute__((ext_vector_type(4))) float f32x4;

static constexpr float FXS  = 16777216.0f;        // 2^24
static constexpr float FXSI = 1.0f / 16777216.0f;

__device__ __forceinline__ unsigned short f2bf(float f) {
    unsigned int u = __float_as_uint(f);
    u += 0x7FFFu + ((u >> 16) & 1u);          // round-to-nearest-even
    return (unsigned short)(u >> 16);
}
__device__ __forceinline__ float bflo(unsigned int w) { return __uint_as_float(w << 16); }
__device__ __forceinline__ float bfhi(unsigned int w) { return __uint_as_float(w & 0xFFFF0000u); }

__device__ __forceinline__ void accum8(float* acc, const uint4 w, float nr) {
    acc[0] = fmaf(bflo(w.x), nr, acc[0]); acc[1] = fmaf(bfhi(w.x), nr, acc[1]);
    acc[2] = fmaf(bflo(w.y), nr, acc[2]); acc[3] = fmaf(bfhi(w.y), nr, acc[3]);
    acc[4] = fmaf(bflo(w.z), nr, acc[4]); acc[5] = fmaf(bfhi(w.z), nr, acc[5]);
    acc[6] = fmaf(bflo(w.w), nr, acc[6]); acc[7] = fmaf(bfhi(w.w), nr, acc[7]);
}

// ---- fused prep: edge pass (x4 batched) + x->bf16 + W->bf16^T -------------
__global__ __launch_bounds__(256) void prep_kernel(
    const int* __restrict__ dst, const float* __restrict__ ew,
    unsigned long long* __restrict__ packed, int* __restrict__ rank, int nE, int eb4,
    const float* __restrict__ X, unsigned short* __restrict__ Xb, int total4, int xbk,
    const float* __restrict__ W1, const float* __restrict__ W2,
    const float* __restrict__ W3, unsigned short* __restrict__ Wt1,
    unsigned short* __restrict__ Wt2, unsigned short* __restrict__ Wt3)
{
    const int b = blockIdx.x;
    if (b < eb4) {                          // --- edge pass: 4 edges/thread
        const int e0 = b * 1024 + threadIdx.x;
        int   d[4]; float w[4]; bool v[4];
#pragma unroll
        for (int u = 0; u < 4; ++u) {
            const int e = e0 + u * 256;
            v[u] = e < nE;
            if (v[u]) { d[u] = dst[e]; w[u] = ew[e]; }
        }
        unsigned long long old[4];
#pragma unroll
        for (int u = 0; u < 4; ++u)         // 4 independent atomics in flight
            if (v[u]) {
                const unsigned long long fx =
                    (unsigned long long)__float2uint_rn(w[u] * FXS);
                old[u] = atomicAdd(&packed[d[u]], (1ULL << 40) | fx);
            }
#pragma unroll
        for (int u = 0; u < 4; ++u)
            if (v[u]) rank[e0 + u * 256] = (int)(old[u] >> 40);
    } else if (b < eb4 + xbk) {             // --- x -> bf16 (BW-bound)
        const int i = (b - eb4) * 256 + threadIdx.x;
        if (i < total4) {
            const float4 v = ((const float4*)X)[i];
            ushort4 o;
            o.x = f2bf(v.x); o.y = f2bf(v.y); o.z = f2bf(v.z); o.w = f2bf(v.w);
            ((ushort4*)Xb)[i] = o;
        }
    } else {                                // --- W -> bf16 transposed (tiny)
        const int i = (b - eb4 - xbk) * 256 + threadIdx.x;
        if (i < 16384) {                    // Wt1[128][128] = W1^T
            const int j = i >> 7, k = i & 127;
            Wt1[i] = f2bf(W1[k * 128 + j]);
        } else if (i < 32768) {             // Wt2
            const int q = i - 16384, j = q >> 7, k = q & 127;
            Wt2[q] = f2bf(W2[k * 128 + j]);
        } else if (i < 40960) {             // Wt3[64][128] = W3^T
            const int q = i - 32768, j = q >> 7, k = q & 127;
            Wt3[q] = f2bf(W3[k * 64 + j]);
        }
    }
}

// ---- dinv from packed + per-block count partials --------------------------
__global__ __launch_bounds__(256) void dinv_partial_kernel(
    const unsigned long long* __restrict__ packed, int* __restrict__ partials,
    float* __restrict__ dinv, int n)
{
    const int b = blockIdx.x;
    const int i = b * 256 + threadIdx.x;
    int c = 0;
    if (i < n) {
        const unsigned long long p = packed[i];
        c = (int)(p >> 40);
        const float deg = (float)(p & ((1ULL << 40) - 1)) * FXSI;
        dinv[i] = rsqrtf(deg + 1.0f);       // +1 = self-loop weight
    }
#pragma unroll
    for (int off = 32; off; off >>= 1) c += __shfl_xor(c, off);
    __shared__ int red[4];
    if ((threadIdx.x & 63) == 0) red[threadIdx.x >> 6] = c;
    __syncthreads();
    if (threadIdx.x == 0) partials[b] = red[0] + red[1] + red[2] + red[3];
}

// ---- exclusive scan of <=256 block partials -------------------------------
__global__ __launch_bounds__(256) void scanp_kernel(
    int* __restrict__ partials, int* __restrict__ rowptr, int n, int nblk)
{
    __shared__ int buf[256];
    const int v = (threadIdx.x < nblk) ? partials[threadIdx.x] : 0;
    buf[threadIdx.x] = v;
    __syncthreads();
    for (int off = 1; off < 256; off <<= 1) {
        const int t = (threadIdx.x >= off) ? buf[threadIdx.x - off] : 0;
        __syncthreads();
        buf[threadIdx.x] += t;
        __syncthreads();
    }
    if (threadIdx.x < nblk) partials[threadIdx.x] = buf[threadIdx.x] - v;  // exclusive
    if (threadIdx.x == 255) rowptr[n] = buf[255];                          // total = E
}

// ---- intra-block scan + offset -> rowptr ----------------------------------
__global__ __launch_bounds__(256) void scanf_kernel(
    const unsigned long long* __restrict__ packed, const int* __restrict__ partials,
    int* __restrict__ rowptr, int n)
{
    __shared__ int buf[256];
    const int b = blockIdx.x;
    const int i = b * 256 + threadIdx.x;
    const int v = (i < n) ? (int)(packed[i] >> 40) : 0;
    buf[threadIdx.x] = v;
    __syncthreads();
    for (int off = 1; off < 256; off <<= 1) {
        const int t = (threadIdx.x >= off) ? buf[threadIdx.x - off] : 0;
        __syncthreads();
        buf[threadIdx.x] += t;
        __syncthreads();
    }
    if (i < n) rowptr[i] = buf[threadIdx.x] - v + partials[b];
}

// ---- device bodies for the fused fill+gemm kernel -------------------------
__device__ __forceinline__ void fill_body(
    const int* __restrict__ src, const int* __restrict__ dst,
    const float* __restrict__ ew, const int* __restrict__ rank,
    const float* __restrict__ dinv, const int* __restrict__ rowptr,
    int2* __restrict__ edges, int nE, int bid, int tid)
{
    const int e0 = bid * 512 + tid;
#pragma unroll
    for (int u = 0; u < 2; ++u) {
        const int e = e0 + u * 256;
        if (e < nE) {
            const int s = src[e], d = dst[e];
            const float nrm = dinv[s] * ew[e] * dinv[d];
            edges[rowptr[d] + rank[e]] = make_int2(s, __float_as_int(nrm));
        }
    }
}

template<int DOUT>
__device__ __forceinline__ void gemm_body(
    const unsigned short* __restrict__ Xb,   // [n][128] bf16
    const unsigned short* __restrict__ Wt,   // [DOUT][128] bf16 (= W^T)
    unsigned short* __restrict__ H, int n, int bid, int tid)
{
    const int wave = tid >> 6;
    const int lane = tid & 63;
    const int row0 = (bid * 4 + wave) * 16;
    if (row0 >= n) return;
    const int lr = lane & 15;            // A row / B col within tile
    const int lk = (lane >> 4) * 8;      // k-offset within 32-wide k-step

    constexpr int NCT = DOUT / 16;
    f32x4 acc[NCT];
#pragma unroll
    for (int c = 0; c < NCT; ++c) acc[c] = (f32x4){0.f, 0.f, 0.f, 0.f};

    const int arow = row0 + lr;
    const bool rv = arow < n;
    short8 afrag[4];
#pragma unroll
    for (int ks = 0; ks < 4; ++ks)
        afrag[ks] = rv ? *(const short8*)(Xb + (size_t)arow * 128 + ks * 32 + lk)
                       : (short8){0, 0, 0, 0, 0, 0, 0, 0};

#pragma unroll
    for (int c = 0; c < NCT; ++c) {
        const unsigned short* wp = Wt + (size_t)(c * 16 + lr) * 128 + lk;
#pragma unroll
        for (int ks = 0; ks < 4; ++ks) {
            const short8 bfrag = *(const short8*)(wp + ks * 32);
            acc[c] = __builtin_amdgcn_mfma_f32_16x16x32_bf16(afrag[ks], bfrag, acc[c], 0, 0, 0);
        }
    }

    const int orow0 = row0 + (lane >> 4) * 4;   // C/D: row = 4*(lane>>4)+r
#pragma unroll
    for (int c = 0; c < NCT; ++c) {
#pragma unroll
        for (int r = 0; r < 4; ++r) {
            const int orow = orow0 + r;
            if (orow < n) H[(size_t)orow * DOUT + c * 16 + lr] = f2bf(acc[c][r]);
        }
    }
}

// ---- fused: CSR fill + layer-1 GEMM (disjoint block ranges) ---------------
__global__ __launch_bounds__(256) void fill_gemm1_kernel(
    const int* __restrict__ src, const int* __restrict__ dst,
    const float* __restrict__ ew, const int* __restrict__ rank,
    const float* __restrict__ dinv, const int* __restrict__ rowptr,
    int2* __restrict__ edges, int nE, int fb,
    const unsigned short* __restrict__ Xb, const unsigned short* __restrict__ Wt,
    unsigned short* __restrict__ H, int n)
{
    if ((int)blockIdx.x < fb)
        fill_body(src, dst, ew, rank, dinv, rowptr, edges, nE, blockIdx.x, threadIdx.x);
    else
        gemm_body<128>(Xb, Wt, H, n, blockIdx.x - fb, threadIdx.x);
}

// ---- standalone MFMA GEMM (layers 2, 3) -----------------------------------
template<int DOUT>
__global__ __launch_bounds__(256) void gemm_mfma_kernel(
    const unsigned short* __restrict__ Xb, const unsigned short* __restrict__ Wt,
    unsigned short* __restrict__ H, int n)
{
    gemm_body<DOUT>(Xb, Wt, H, n, blockIdx.x, threadIdx.x);
}

// -- gather + self-loop/bias + LayerNorm(+ReLU): one GS-lane group per node --
// GS = D/8 lanes per node; each lane owns 8 bf16 (one dwordx4 per edge-row).
template<int D, bool RELU, bool OB16>
__global__ __launch_bounds__(256) void gather_ln_kernel(
    const unsigned short* __restrict__ H, const int2* __restrict__ edges,
    const int* __restrict__ rowptr, const float* __restrict__ dinv,
    const float* __restrict__ bias, const float* __restrict__ g,
    const float* __restrict__ t, void* __restrict__ OUT, int n)
{
    constexpr int GS  = D / 8;           // lanes per node (16 or 8)
    constexpr int NPW = 64 / GS;         // nodes per wave (4 or 8)
    const int lane = threadIdx.x & 63;
    const int wave = threadIdx.x >> 6;
    const int L    = lane & (GS - 1);    // lane within group
    const int gb0  = lane & ~(GS - 1);   // group's base lane (abs, wave-wide)
    const int node = (blockIdx.x * 4 + wave) * NPW + (lane >> (GS == 16 ? 4 : 3));
    if (node >= n) return;

    const float di = dinv[node];
    const float sn = di * di;            // self-loop norm = 1/deg
    float acc[8];
    {
        const uint4 w = *(const uint4*)(H + (size_t)node * D + L * 8);
        const float4 b0 = *(const float4*)(bias + L * 8);
        const float4 b1 = *(const float4*)(bias + L * 8 + 4);
        acc[0] = fmaf(bflo(w.x), sn, b0.x); acc[1] = fmaf(bfhi(w.x), sn, b0.y);
        acc[2] = fmaf(bflo(w.y), sn, b0.z); acc[3] = fmaf(bfhi(w.y), sn, b0.w);
        acc[4] = fmaf(bflo(w.z), sn, b1.x); acc[5] = fmaf(bfhi(w.z), sn, b1.y);
        acc[6] = fmaf(bflo(w.w), sn, b1.z); acc[7] = fmaf(bfhi(w.w), sn, b1.w);
    }

    const int k0 = rowptr[node], k1 = rowptr[node + 1];
    for (int base = k0; base < k1; base += GS) {
        int2 ed = make_int2(0, 0);
        if (base + L < k1) ed = edges[base + L];
        const int cnt = min(GS, k1 - base);
        int j = 0;
        for (; j + 4 <= cnt; j += 4) {   // 4 row-loads in flight per group
            int s[4]; float nr[4]; uint4 w[4];
#pragma unroll
            for (int u = 0; u < 4; ++u) {
                s[u]  = __shfl(ed.x, gb0 + j + u);
                nr[u] = __int_as_float(__shfl(ed.y, gb0 + j + u));
            }
#pragma unroll
            for (int u = 0; u < 4; ++u)
                w[u] = *(const uint4*)(H + (size_t)s[u] * D + L * 8);
#pragma unroll
            for (int u = 0; u < 4; ++u) accum8(acc, w[u], nr[u]);
        }
        for (; j < cnt; ++j) {
            const int   s0 = __shfl(ed.x, gb0 + j);
            const float n0 = __int_as_float(__shfl(ed.y, gb0 + j));
            const uint4 w0 = *(const uint4*)(H + (size_t)s0 * D + L * 8);
            accum8(acc, w0, n0);
        }
    }

    // LayerNorm across the GS-lane group (full row in group registers)
    float s1 = 0.f;
#pragma unroll
    for (int i = 0; i < 8; ++i) s1 += acc[i];
#pragma unroll
    for (int off = GS / 2; off; off >>= 1) s1 += __shfl_xor(s1, off);
    const float m = s1 * (1.f / D);
    float s2 = 0.f;
#pragma unroll
    for (int i = 0; i < 8; ++i) { acc[i] -= m; s2 += acc[i] * acc[i]; }
#pragma unroll
    for (int off = GS / 2; off; off >>= 1) s2 += __shfl_xor(s2, off);
    const float rs = rsqrtf(s2 * (1.f / D) + 1e-5f);

    const float4 g0 = *(const float4*)(g + L * 8), g1 = *(const float4*)(g + L * 8 + 4);
    const float4 t0 = *(const float4*)(t + L * 8), t1 = *(const float4*)(t + L * 8 + 4);
    float r[8];
    r[0] = fmaf(acc[0] * rs, g0.x, t0.x); r[1] = fmaf(acc[1] * rs, g0.y, t0.y);
    r[2] = fmaf(acc[2] * rs, g0.z, t0.z); r[3] = fmaf(acc[3] * rs, g0.w, t0.w);
    r[4] = fmaf(acc[4] * rs, g1.x, t1.x); r[5] = fmaf(acc[5] * rs, g1.y, t1.y);
    r[6] = fmaf(acc[6] * rs, g1.z, t1.z); r[7] = fmaf(acc[7] * rs, g1.w, t1.w);
    if (RELU) {
#pragma unroll
        for (int i = 0; i < 8; ++i) r[i] = fmaxf(r[i], 0.f);
    }

    if constexpr (OB16) {
        uint4 o;
        o.x = (unsigned int)f2bf(r[0]) | ((unsigned int)f2bf(r[1]) << 16);
        o.y = (unsigned int)f2bf(r[2]) | ((unsigned int)f2bf(r[3]) << 16);
        o.z = (unsigned int)f2bf(r[4]) | ((unsigned int)f2bf(r[5]) << 16);
        o.w = (unsigned int)f2bf(r[6]) | ((unsigned int)f2bf(r[7]) << 16);
        *(uint4*)((unsigned short*)OUT + (size_t)node * D + L * 8) = o;
    } else {
        float* o = (float*)OUT + (size_t)node * D + L * 8;
        *(float4*)o       = make_float4(r[0], r[1], r[2], r[3]);
        *(float4*)(o + 4) = make_float4(r[4], r[5], r[6], r[7]);
    }
}

// ---------------------------------------------------------------------------
extern "C" void kernel_launch(void* const* d_in, const int* in_sizes, int n_in,
                              void* d_out, int out_size, void* d_ws, size_t ws_size,
                              hipStream_t stream)
{
    const float* x  = (const float*)d_in[0];
    const int*   ei = (const int*)  d_in[1];
    const float* ew = (const float*)d_in[2];
    const float* W1 = (const float*)d_in[3];
    const float* b1 = (const float*)d_in[4];
    const float* g1 = (const float*)d_in[5];
    const float* t1 = (const float*)d_in[6];
    const float* W2 = (const float*)d_in[7];
    const float* b2 = (const float*)d_in[8];
    const float* g2 = (const float*)d_in[9];
    const float* t2 = (const float*)d_in[10];
    const float* W3 = (const float*)d_in[11];
    const float* b3 = (const float*)d_in[12];
    const float* g3 = (const float*)d_in[13];
    const float* t3 = (const float*)d_in[14];

    const int n  = in_sizes[0] / 128;
    const int nE = in_sizes[1] / 2;
    const int* srcv = ei;           // edge_index[0]
    const int* dstv = ei + nE;      // edge_index[1]

    const size_t na   = ((size_t)n + 63) & ~(size_t)63;
    const int    nblk = (n + 255) / 256;    // scan blocks (<=256 required; 196 here)
    const int    eb4  = (nE + 1023) / 1024; // edge-pass blocks (4 edges/thread)
    const int    xbk  = (n * 32 + 255) / 256;
    const int    fb   = (nE + 511) / 512;   // fill blocks (2 edges/thread)

    // ws: packed[na] u64 | dinv[na] f32 | rowptr[na+64] i32 | partials[256] i32 |
    //     edges[E] int2 | Hb[n*128] bf16 | Qb[n*128] bf16 | xb[n*128] bf16 |
    //     Wt1/Wt2/Wt3 bf16.
    // rank[nE] overlays Qb: free until gather1 writes Qb, which is strictly
    // after fill_gemm1 (fill reads rank concurrent with gemm writing Hb).
    unsigned long long* packed = (unsigned long long*)d_ws;
    float* dinv     = (float*)(packed + na);
    int*   rowptr   = (int*)(dinv + na);
    int*   partials = rowptr + na + 64;
    int2*  edges    = (int2*)(partials + 256);
    unsigned short* Hb  = (unsigned short*)(edges + nE);
    unsigned short* Qb  = Hb + (size_t)n * 128;
    unsigned short* xb  = Qb + (size_t)n * 128;
    unsigned short* Wt1 = xb + (size_t)n * 128;
    unsigned short* Wt2 = Wt1 + 16384;
    unsigned short* Wt3 = Wt2 + 16384;
    int* rank = (int*)Qb;                   // NOT Hb (gemm1 writes Hb in parallel)

    hipMemsetAsync(packed, 0, na * sizeof(unsigned long long), stream);

    // fused prep: edge pass + x/W converts (disjoint block ranges)
    prep_kernel<<<eb4 + xbk + 160, 256, 0, stream>>>(
        dstv, ew, packed, rank, nE, eb4,
        x, xb, n * 32, xbk, W1, W2, W3, Wt1, Wt2, Wt3);
    dinv_partial_kernel<<<nblk, 256, 0, stream>>>(packed, partials, dinv, n);
    scanp_kernel       <<<1,    256, 0, stream>>>(partials, rowptr, n, nblk);
    scanf_kernel       <<<nblk, 256, 0, stream>>>(packed, partials, rowptr, n);

    const int gb   = (n + 63) / 64;         // gemm: 16 rows/wave * 4 waves
    const int nbA  = (n + 15) / 16;         // gather D=128: 16 nodes/block
    const int nbB  = (n + 31) / 32;         // gather D=64:  32 nodes/block

    // Layer 1: CSR fill + GEMM fused -> Hb; then gather -> Qb
    fill_gemm1_kernel<<<fb + gb, 256, 0, stream>>>(
        srcv, dstv, ew, rank, dinv, rowptr, edges, nE, fb, xb, Wt1, Hb, n);
    gather_ln_kernel<128, true, true><<<nbA, 256, 0, stream>>>(Hb, edges, rowptr, dinv, b1, g1, t1, Qb, n);

    // Layer 2: Qb -> Hb -> Qb
    gemm_mfma_kernel<128><<<gb, 256, 0, stream>>>(Qb, Wt2, Hb, n);
    gather_ln_kernel<128, true, true><<<nbA, 256, 0, stream>>>(Hb, edges, rowptr, dinv, b2, g2, t2, Qb, n);

    // Layer 3: Qb -> Hb(n*64) -> d_out (f32)
    gemm_mfma_kernel<64><<<gb, 256, 0, stream>>>(Qb, Wt3, Hb, n);
    gather_ln_kernel<64, false, false><<<nbB, 256, 0, stream>>>(Hb, edges, rowptr, dinv, b3, g3, t3, d_out, n);
}

// Round 11
// 276.342 us; speedup vs baseline: 13.1762x; 1.0812x over previous
//
#include <hip/hip_runtime.h>

// ---------------------------------------------------------------------------
// SpatialGCN: 3x (GCNConv -> LayerNorm -> ReLU[except last])
// N=50000, E=800000, dims 128->128->128->64, f32 in/out.
//
// R10 change (post-mortem: x4 atomic batching was NULL -- device atomics are
// throughput-capped at ~20G/s chip-wide; 800K edge atomics => >=40us floor):
// CSR build rewritten as bucketed two-pass with LDS atomics:
//   kA: per-block LDS bucket histogram (bucket = dst>>7) -> ~77K global atomics
//       (fused with x->bf16 and W->bf16^T converts)
//   kB: 1-block scan of bucket counts -> bukBase/bukCur, rowptr[n]=E
//   kC: scatter (src,ew,dstLow7) into bucket-ordered staging (LDS-ordered,
//       1 global atomic per block-bucket pair) -- fused with layer-1 GEMM
//   kD: one block per bucket (exclusive dst ownership): LDS count/rank/degsum,
//       LDS scan -> rowptr/dinv, write final CSR. ZERO per-edge global atomics.
// Edges store ew*dinv[dst]; gather multiplies dinv[src] on the fly (dinv is
// 200KB, L2-hot).
// ---------------------------------------------------------------------------

typedef __attribute__((ext_vector_type(8))) short short8;
typedef __attribute__((ext_vector_type(4))) float f32x4;

__device__ __forceinline__ unsigned short f2bf(float f) {
    unsigned int u = __float_as_uint(f);
    u += 0x7FFFu + ((u >> 16) & 1u);          // round-to-nearest-even
    return (unsigned short)(u >> 16);
}
__device__ __forceinline__ float bflo(unsigned int w) { return __uint_as_float(w << 16); }
__device__ __forceinline__ float bfhi(unsigned int w) { return __uint_as_float(w & 0xFFFF0000u); }

__device__ __forceinline__ void accum8(float* acc, const uint4 w, float nr) {
    acc[0] = fmaf(bflo(w.x), nr, acc[0]); acc[1] = fmaf(bfhi(w.x), nr, acc[1]);
    acc[2] = fmaf(bflo(w.y), nr, acc[2]); acc[3] = fmaf(bfhi(w.y), nr, acc[3]);
    acc[4] = fmaf(bflo(w.z), nr, acc[4]); acc[5] = fmaf(bfhi(w.z), nr, acc[5]);
    acc[6] = fmaf(bflo(w.w), nr, acc[6]); acc[7] = fmaf(bfhi(w.w), nr, acc[7]);
}

// ---- kA: bucket histogram (LDS) + x->bf16 + W->bf16^T ---------------------
__global__ __launch_bounds__(256) void prep_kernel(
    const int* __restrict__ dst, int* __restrict__ bukCnt, int nE, int ebA,
    const float* __restrict__ X, unsigned short* __restrict__ Xb, int total4, int xbk,
    const float* __restrict__ W1, const float* __restrict__ W2,
    const float* __restrict__ W3, unsigned short* __restrict__ Wt1,
    unsigned short* __restrict__ Wt2, unsigned short* __restrict__ Wt3)
{
    const int b = blockIdx.x;
    if (b < ebA) {                          // --- bucket histogram, 16 edges/thr
        __shared__ int h[512];
        for (int i = threadIdx.x; i < 512; i += 256) h[i] = 0;
        __syncthreads();
        const int e0 = b * 4096 + threadIdx.x;
#pragma unroll
        for (int u = 0; u < 16; ++u) {
            const int e = e0 + u * 256;
            if (e < nE) atomicAdd(&h[dst[e] >> 7], 1);
        }
        __syncthreads();
        for (int i = threadIdx.x; i < 512; i += 256)
            if (h[i]) atomicAdd(&bukCnt[i], h[i]);
    } else if (b < ebA + xbk) {             // --- x -> bf16 (BW-bound)
        const int i = (b - ebA) * 256 + threadIdx.x;
        if (i < total4) {
            const float4 v = ((const float4*)X)[i];
            ushort4 o;
            o.x = f2bf(v.x); o.y = f2bf(v.y); o.z = f2bf(v.z); o.w = f2bf(v.w);
            ((ushort4*)Xb)[i] = o;
        }
    } else {                                // --- W -> bf16 transposed (tiny)
        const int i = (b - ebA - xbk) * 256 + threadIdx.x;
        if (i < 16384) {                    // Wt1[128][128] = W1^T
            const int j = i >> 7, k = i & 127;
            Wt1[i] = f2bf(W1[k * 128 + j]);
        } else if (i < 32768) {             // Wt2
            const int q = i - 16384, j = q >> 7, k = q & 127;
            Wt2[q] = f2bf(W2[k * 128 + j]);
        } else if (i < 40960) {             // Wt3[64][128] = W3^T
            const int q = i - 32768, j = q >> 7, k = q & 127;
            Wt3[q] = f2bf(W3[k * 64 + j]);
        }
    }
}

// ---- kB: exclusive scan of bucket counts ----------------------------------
__global__ __launch_bounds__(512) void bukscan_kernel(
    const int* __restrict__ bukCnt, int* __restrict__ bukBase,
    int* __restrict__ bukCur, int* __restrict__ rowptr, int n, int nbuk, int nE)
{
    __shared__ int buf[512];
    const int v = (threadIdx.x < nbuk) ? bukCnt[threadIdx.x] : 0;
    buf[threadIdx.x] = v;
    __syncthreads();
    for (int off = 1; off < 512; off <<= 1) {
        const int t = (threadIdx.x >= off) ? buf[threadIdx.x - off] : 0;
        __syncthreads();
        buf[threadIdx.x] += t;
        __syncthreads();
    }
    if (threadIdx.x < nbuk) {
        const int ex = buf[threadIdx.x] - v;
        bukBase[threadIdx.x] = ex;
        bukCur[threadIdx.x]  = ex;
        if (threadIdx.x == nbuk - 1) bukBase[nbuk] = buf[threadIdx.x];
    }
    if (threadIdx.x == 0) rowptr[n] = nE;
}

// ---- MFMA GEMM body -------------------------------------------------------
template<int DOUT>
__device__ __forceinline__ void gemm_body(
    const unsigned short* __restrict__ Xb,   // [n][128] bf16
    const unsigned short* __restrict__ Wt,   // [DOUT][128] bf16 (= W^T)
    unsigned short* __restrict__ H, int n, int bid, int tid)
{
    const int wave = tid >> 6;
    const int lane = tid & 63;
    const int row0 = (bid * 4 + wave) * 16;
    if (row0 >= n) return;
    const int lr = lane & 15;            // A row / B col within tile
    const int lk = (lane >> 4) * 8;      // k-offset within 32-wide k-step

    constexpr int NCT = DOUT / 16;
    f32x4 acc[NCT];
#pragma unroll
    for (int c = 0; c < NCT; ++c) acc[c] = (f32x4){0.f, 0.f, 0.f, 0.f};

    const int arow = row0 + lr;
    const bool rv = arow < n;
    short8 afrag[4];
#pragma unroll
    for (int ks = 0; ks < 4; ++ks)
        afrag[ks] = rv ? *(const short8*)(Xb + (size_t)arow * 128 + ks * 32 + lk)
                       : (short8){0, 0, 0, 0, 0, 0, 0, 0};

#pragma unroll
    for (int c = 0; c < NCT; ++c) {
        const unsigned short* wp = Wt + (size_t)(c * 16 + lr) * 128 + lk;
#pragma unroll
        for (int ks = 0; ks < 4; ++ks) {
            const short8 bfrag = *(const short8*)(wp + ks * 32);
            acc[c] = __builtin_amdgcn_mfma_f32_16x16x32_bf16(afrag[ks], bfrag, acc[c], 0, 0, 0);
        }
    }

    const int orow0 = row0 + (lane >> 4) * 4;   // C/D: row = 4*(lane>>4)+r
#pragma unroll
    for (int c = 0; c < NCT; ++c) {
#pragma unroll
        for (int r = 0; r < 4; ++r) {
            const int orow = orow0 + r;
            if (orow < n) H[(size_t)orow * DOUT + c * 16 + lr] = f2bf(acc[c][r]);
        }
    }
}

// ---- kC: scatter records to bucket order + layer-1 GEMM (disjoint ranges) --
__global__ __launch_bounds__(256) void scat_gemm1_kernel(
    const int* __restrict__ src, const int* __restrict__ dst,
    const float* __restrict__ ew, int* __restrict__ bukCur,
    int2* __restrict__ rec, unsigned char* __restrict__ rdst, int nE, int ebA,
    const unsigned short* __restrict__ Xb, const unsigned short* __restrict__ Wt,
    unsigned short* __restrict__ H, int n)
{
    if ((int)blockIdx.x < ebA) {
        __shared__ int h[512], res[512], cur[512];
        for (int i = threadIdx.x; i < 512; i += 256) { h[i] = 0; cur[i] = 0; }
        __syncthreads();
        const int e0 = blockIdx.x * 4096 + threadIdx.x;
        int sv[16], dv[16], bk[16]; float wv[16]; bool va[16];
#pragma unroll
        for (int u = 0; u < 16; ++u) {
            const int e = e0 + u * 256;
            va[u] = e < nE;
            if (va[u]) {
                sv[u] = src[e]; dv[u] = dst[e]; wv[u] = ew[e];
                bk[u] = dv[u] >> 7;
                atomicAdd(&h[bk[u]], 1);
            }
        }
        __syncthreads();
        for (int i = threadIdx.x; i < 512; i += 256)
            res[i] = h[i] ? atomicAdd(&bukCur[i], h[i]) : 0;   // reserve range
        __syncthreads();
#pragma unroll
        for (int u = 0; u < 16; ++u) {
            if (va[u]) {
                const int r   = atomicAdd(&cur[bk[u]], 1);
                const int pos = res[bk[u]] + r;
                rec[pos]  = make_int2(sv[u], __float_as_int(wv[u]));
                rdst[pos] = (unsigned char)(dv[u] & 127);
            }
        }
    } else {
        gemm_body<128>(Xb, Wt, H, n, blockIdx.x - ebA, threadIdx.x);
    }
}

// ---- kD: per-bucket CSR finalize (LDS atomics only) -----------------------
__global__ __launch_bounds__(256) void csrfin_kernel(
    const int2* __restrict__ rec, const unsigned char* __restrict__ rdst,
    const int* __restrict__ bukBase, int* __restrict__ rowptr,
    float* __restrict__ dinv, int2* __restrict__ edges, int n)
{
    __shared__ int   cnt[128];
    __shared__ float deg[128];
    __shared__ int   sc[128];
    __shared__ float dvl[128];
    const int b  = blockIdx.x;
    const int lo = bukBase[b], hi = bukBase[b + 1];
    if (threadIdx.x < 128) { cnt[threadIdx.x] = 0; deg[threadIdx.x] = 0.f; }
    __syncthreads();
    for (int i = lo + (int)threadIdx.x; i < hi; i += 256) {   // count + deg-sum
        const int dl = rdst[i];
        atomicAdd(&cnt[dl], 1);
        atomicAdd(&deg[dl], __int_as_float(rec[i].y));
    }
    __syncthreads();
    {   // exclusive scan cnt -> sc
        const int v = (threadIdx.x < 128) ? cnt[threadIdx.x] : 0;
        if (threadIdx.x < 128) sc[threadIdx.x] = v;
        __syncthreads();
        for (int off = 1; off < 128; off <<= 1) {
            const int t = (threadIdx.x < 128 && (int)threadIdx.x >= off)
                        ? sc[threadIdx.x - off] : 0;
            __syncthreads();
            if (threadIdx.x < 128) sc[threadIdx.x] += t;
            __syncthreads();
        }
        if (threadIdx.x < 128) sc[threadIdx.x] -= v;
    }
    if (threadIdx.x < 128) {
        const int d = b * 128 + (int)threadIdx.x;
        if (d < n) {
            rowptr[d] = lo + sc[threadIdx.x];
            const float di = rsqrtf(deg[threadIdx.x] + 1.0f);  // +1 = self-loop
            dinv[d] = di;
            dvl[threadIdx.x] = di;
        }
        cnt[threadIdx.x] = 0;                  // reuse as phase-2 cursor
    }
    __syncthreads();
    for (int i = lo + (int)threadIdx.x; i < hi; i += 256) {   // final CSR write
        const int dl = rdst[i];
        const int2 r = rec[i];
        const int rk = atomicAdd(&cnt[dl], 1);
        edges[lo + sc[dl] + rk] =
            make_int2(r.x, __float_as_int(__int_as_float(r.y) * dvl[dl]));
    }
}

// ---- standalone MFMA GEMM (layers 2, 3) -----------------------------------
template<int DOUT>
__global__ __launch_bounds__(256) void gemm_mfma_kernel(
    const unsigned short* __restrict__ Xb, const unsigned short* __restrict__ Wt,
    unsigned short* __restrict__ H, int n)
{
    gemm_body<DOUT>(Xb, Wt, H, n, blockIdx.x, threadIdx.x);
}

// -- gather + self-loop/bias + LayerNorm(+ReLU): one GS-lane group per node --
// GS = D/8 lanes per node; each lane owns 8 bf16 (one dwordx4 per edge-row).
// edges[e] = (src, ew*dinv[dst]); nrm = that * dinv[src] (dinv is L2-hot).
template<int D, bool RELU, bool OB16>
__global__ __launch_bounds__(256) void gather_ln_kernel(
    const unsigned short* __restrict__ H, const int2* __restrict__ edges,
    const int* __restrict__ rowptr, const float* __restrict__ dinv,
    const float* __restrict__ bias, const float* __restrict__ g,
    const float* __restrict__ t, void* __restrict__ OUT, int n)
{
    constexpr int GS  = D / 8;           // lanes per node (16 or 8)
    constexpr int NPW = 64 / GS;         // nodes per wave (4 or 8)
    const int lane = threadIdx.x & 63;
    const int wave = threadIdx.x >> 6;
    const int L    = lane & (GS - 1);    // lane within group
    const int gb0  = lane & ~(GS - 1);   // group's base lane (abs, wave-wide)
    const int node = (blockIdx.x * 4 + wave) * NPW + (lane >> (GS == 16 ? 4 : 3));
    if (node >= n) return;

    const float di = dinv[node];
    const float sn = di * di;            // self-loop norm = 1/deg
    float acc[8];
    {
        const uint4 w = *(const uint4*)(H + (size_t)node * D + L * 8);
        const float4 b0 = *(const float4*)(bias + L * 8);
        const float4 b1 = *(const float4*)(bias + L * 8 + 4);
        acc[0] = fmaf(bflo(w.x), sn, b0.x); acc[1] = fmaf(bfhi(w.x), sn, b0.y);
        acc[2] = fmaf(bflo(w.y), sn, b0.z); acc[3] = fmaf(bfhi(w.y), sn, b0.w);
        acc[4] = fmaf(bflo(w.z), sn, b1.x); acc[5] = fmaf(bfhi(w.z), sn, b1.y);
        acc[6] = fmaf(bflo(w.w), sn, b1.z); acc[7] = fmaf(bfhi(w.w), sn, b1.w);
    }

    const int k0 = rowptr[node], k1 = rowptr[node + 1];
    for (int base = k0; base < k1; base += GS) {
        int2 ed = make_int2(0, 0); float cm = 0.f;
        if (base + L < k1) {
            ed = edges[base + L];
            cm = __int_as_float(ed.y) * dinv[ed.x];   // full norm, L2-hot load
        }
        const int cnt = min(GS, k1 - base);
        int j = 0;
        for (; j + 4 <= cnt; j += 4) {   // 4 row-loads in flight per group
            int s[4]; float nr[4]; uint4 w[4];
#pragma unroll
            for (int u = 0; u < 4; ++u) {
                s[u]  = __shfl(ed.x, gb0 + j + u);
                nr[u] = __shfl(cm,  gb0 + j + u);
            }
#pragma unroll
            for (int u = 0; u < 4; ++u)
                w[u] = *(const uint4*)(H + (size_t)s[u] * D + L * 8);
#pragma unroll
            for (int u = 0; u < 4; ++u) accum8(acc, w[u], nr[u]);
        }
        for (; j < cnt; ++j) {
            const int   s0 = __shfl(ed.x, gb0 + j);
            const float n0 = __shfl(cm,  gb0 + j);
            const uint4 w0 = *(const uint4*)(H + (size_t)s0 * D + L * 8);
            accum8(acc, w0, n0);
        }
    }

    // LayerNorm across the GS-lane group (full row in group registers)
    float s1 = 0.f;
#pragma unroll
    for (int i = 0; i < 8; ++i) s1 += acc[i];
#pragma unroll
    for (int off = GS / 2; off; off >>= 1) s1 += __shfl_xor(s1, off);
    const float m = s1 * (1.f / D);
    float s2 = 0.f;
#pragma unroll
    for (int i = 0; i < 8; ++i) { acc[i] -= m; s2 += acc[i] * acc[i]; }
#pragma unroll
    for (int off = GS / 2; off; off >>= 1) s2 += __shfl_xor(s2, off);
    const float rs = rsqrtf(s2 * (1.f / D) + 1e-5f);

    const float4 g0 = *(const float4*)(g + L * 8), g1 = *(const float4*)(g + L * 8 + 4);
    const float4 t0 = *(const float4*)(t + L * 8), t1 = *(const float4*)(t + L * 8 + 4);
    float r[8];
    r[0] = fmaf(acc[0] * rs, g0.x, t0.x); r[1] = fmaf(acc[1] * rs, g0.y, t0.y);
    r[2] = fmaf(acc[2] * rs, g0.z, t0.z); r[3] = fmaf(acc[3] * rs, g0.w, t0.w);
    r[4] = fmaf(acc[4] * rs, g1.x, t1.x); r[5] = fmaf(acc[5] * rs, g1.y, t1.y);
    r[6] = fmaf(acc[6] * rs, g1.z, t1.z); r[7] = fmaf(acc[7] * rs, g1.w, t1.w);
    if (RELU) {
#pragma unroll
        for (int i = 0; i < 8; ++i) r[i] = fmaxf(r[i], 0.f);
    }

    if constexpr (OB16) {
        uint4 o;
        o.x = (unsigned int)f2bf(r[0]) | ((unsigned int)f2bf(r[1]) << 16);
        o.y = (unsigned int)f2bf(r[2]) | ((unsigned int)f2bf(r[3]) << 16);
        o.z = (unsigned int)f2bf(r[4]) | ((unsigned int)f2bf(r[5]) << 16);
        o.w = (unsigned int)f2bf(r[6]) | ((unsigned int)f2bf(r[7]) << 16);
        *(uint4*)((unsigned short*)OUT + (size_t)node * D + L * 8) = o;
    } else {
        float* o = (float*)OUT + (size_t)node * D + L * 8;
        *(float4*)o       = make_float4(r[0], r[1], r[2], r[3]);
        *(float4*)(o + 4) = make_float4(r[4], r[5], r[6], r[7]);
    }
}

// ---------------------------------------------------------------------------
extern "C" void kernel_launch(void* const* d_in, const int* in_sizes, int n_in,
                              void* d_out, int out_size, void* d_ws, size_t ws_size,
                              hipStream_t stream)
{
    const float* x  = (const float*)d_in[0];
    const int*   ei = (const int*)  d_in[1];
    const float* ew = (const float*)d_in[2];
    const float* W1 = (const float*)d_in[3];
    const float* b1 = (const float*)d_in[4];
    const float* g1 = (const float*)d_in[5];
    const float* t1 = (const float*)d_in[6];
    const float* W2 = (const float*)d_in[7];
    const float* b2 = (const float*)d_in[8];
    const float* g2 = (const float*)d_in[9];
    const float* t2 = (const float*)d_in[10];
    const float* W3 = (const float*)d_in[11];
    const float* b3 = (const float*)d_in[12];
    const float* g3 = (const float*)d_in[13];
    const float* t3 = (const float*)d_in[14];

    const int n  = in_sizes[0] / 128;
    const int nE = in_sizes[1] / 2;
    const int* srcv = ei;                   // edge_index[0]
    const int* dstv = ei + nE;              // edge_index[1]

    const size_t na   = ((size_t)n + 63) & ~(size_t)63;
    const int    nbuk = (n + 127) >> 7;     // 391 buckets (requires n <= 65536)
    const int    ebA  = (nE + 4095) / 4096; // edge blocks (16 edges/thread)
    const int    xbk  = (n * 32 + 255) / 256;

    // ws: dinv[na] f32 | rowptr[na+64] | bukCnt[512] | bukBase[576] | bukCur[512]
    //     | edges[nE] int2 | Hb[n*128] bf16 | Qb[n*128] bf16 | xb[n*128] bf16
    //     | Wt1/Wt2/Wt3 bf16.
    // rec[nE] int2 + rdst[nE] u8 (7.2MB) overlay Qb (12.8MB): consumed by kD,
    // which completes strictly before gather1 writes Qb.
    float* dinv     = (float*)d_ws;
    int*   rowptr   = (int*)(dinv + na);
    int*   bukCnt   = rowptr + na + 64;
    int*   bukBase  = bukCnt + 512;
    int*   bukCur   = bukBase + 576;
    int2*  edges    = (int2*)(bukCur + 512);
    unsigned short* Hb  = (unsigned short*)(edges + nE);
    unsigned short* Qb  = Hb + (size_t)n * 128;
    unsigned short* xb  = Qb + (size_t)n * 128;
    unsigned short* Wt1 = xb + (size_t)n * 128;
    unsigned short* Wt2 = Wt1 + 16384;
    unsigned short* Wt3 = Wt2 + 16384;
    int2* rec = (int2*)Qb;
    unsigned char* rdst = (unsigned char*)(rec + nE);

    hipMemsetAsync(bukCnt, 0, 512 * sizeof(int), stream);

    // kA: bucket histogram + x/W converts (disjoint block ranges)
    prep_kernel<<<ebA + xbk + 160, 256, 0, stream>>>(
        dstv, bukCnt, nE, ebA, x, xb, n * 32, xbk, W1, W2, W3, Wt1, Wt2, Wt3);
    // kB: scan bucket counts
    bukscan_kernel<<<1, 512, 0, stream>>>(bukCnt, bukBase, bukCur, rowptr, n, nbuk, nE);

    const int gb  = (n + 63) / 64;          // gemm: 16 rows/wave * 4 waves
    const int nbA = (n + 15) / 16;          // gather D=128: 16 nodes/block
    const int nbB = (n + 31) / 32;          // gather D=64:  32 nodes/block

    // kC: scatter to bucket order + layer-1 GEMM (xb -> Hb)
    scat_gemm1_kernel<<<ebA + gb, 256, 0, stream>>>(
        srcv, dstv, ew, bukCur, rec, rdst, nE, ebA, xb, Wt1, Hb, n);
    // kD: per-bucket CSR finalize -> edges, rowptr, dinv
    csrfin_kernel<<<nbuk, 256, 0, stream>>>(rec, rdst, bukBase, rowptr, dinv, edges, n);

    // Layer 1 gather: Hb -> Qb
    gather_ln_kernel<128, true, true><<<nbA, 256, 0, stream>>>(Hb, edges, rowptr, dinv, b1, g1, t1, Qb, n);

    // Layer 2: Qb -> Hb -> Qb
    gemm_mfma_kernel<128><<<gb, 256, 0, stream>>>(Qb, Wt2, Hb, n);
    gather_ln_kernel<128, true, true><<<nbA, 256, 0, stream>>>(Hb, edges, rowptr, dinv, b2, g2, t2, Qb, n);

    // Layer 3: Qb -> Hb(n*64) -> d_out (f32)
    gemm_mfma_kernel<64><<<gb, 256, 0, stream>>>(Qb, Wt3, Hb, n);
    gather_ln_kernel<64, false, false><<<nbB, 256, 0, stream>>>(Hb, edges, rowptr, dinv, b3, g3, t3, d_out, n);
}